// Round 1
// baseline (1132.426 us; speedup 1.0000x reference)
//
#include <hip/hip_runtime.h>
#include <math.h>

// Layout constants: B=2, C=64, T=16, H=W=64, S=3, r=4
// x index: ((b*64+c)*16+t)*4096 + h*64+w ; frame n in [0,32): b=n>>4, t=n&15

__device__ __forceinline__ float sigmoidf_(float v) {
    return 1.0f / (1.0f + expf(-v));
}

// Bilinear sample setup matching reference grid_sample semantics.
struct Samp { int o0, o1, o2, o3; float w0, w1, w2, w3; };

__device__ __forceinline__ Samp make_samp(float ox, float oy, int w, int h) {
    float bx = (2.0f * (float)w) / 63.0f - 1.0f;
    float by = (2.0f * (float)h) / 63.0f - 1.0f;
    float vx = bx + ox / 63.0f;
    float vy = by + oy / 63.0f;
    float gx = ((vx + 1.0f) * 64.0f - 1.0f) * 0.5f;
    float gy = ((vy + 1.0f) * 64.0f - 1.0f) * 0.5f;
    float fx = floorf(gx), fy = floorf(gy);
    float wx = gx - fx, wy = gy - fy;
    int x0 = (int)fx, y0 = (int)fy;
    int x1 = x0 + 1, y1 = y0 + 1;
    bool vx0 = (x0 >= 0) && (x0 < 64), vx1 = (x1 >= 0) && (x1 < 64);
    bool vy0 = (y0 >= 0) && (y0 < 64), vy1 = (y1 >= 0) && (y1 < 64);
    int cx0 = min(max(x0, 0), 63), cx1 = min(max(x1, 0), 63);
    int cy0 = min(max(y0, 0), 63), cy1 = min(max(y1, 0), 63);
    Samp s;
    s.o0 = cy0 * 64 + cx0; s.w0 = (1.0f - wx) * (1.0f - wy) * ((vx0 && vy0) ? 1.0f : 0.0f);
    s.o1 = cy0 * 64 + cx1; s.w1 = wx * (1.0f - wy) * ((vx1 && vy0) ? 1.0f : 0.0f);
    s.o2 = cy1 * 64 + cx0; s.w2 = (1.0f - wx) * wy * ((vx0 && vy1) ? 1.0f : 0.0f);
    s.o3 = cy1 * 64 + cx1; s.w3 = wx * wy * ((vx1 && vy1) ? 1.0f : 0.0f);
    return s;
}

// ---------- 1x1x1 down conv: x (B,64,T,H,W) -> x_agg (B,4,T,H,W) ----------
__global__ __launch_bounds__(256) void k_down(const float* __restrict__ x,
                                              const float* __restrict__ dw,
                                              float* __restrict__ xa)
{
    int gid = blockIdx.x * 256 + threadIdx.x;   // 131072 = 32*4096
    int hw = gid & 4095;
    int bt = gid >> 12;
    int b = bt >> 4, t = bt & 15;
    float a0 = 0.f, a1 = 0.f, a2 = 0.f, a3 = 0.f;
    const float* xp = x + (((size_t)b * 64) * 16 + t) * 4096 + hw;
    for (int c = 0; c < 64; c++) {
        float v = xp[(size_t)c * 65536];
        a0 = fmaf(v, dw[c], a0);
        a1 = fmaf(v, dw[64 + c], a1);
        a2 = fmaf(v, dw[128 + c], a2);
        a3 = fmaf(v, dw[192 + c], a3);
    }
    size_t base = (((size_t)b * 4) * 16 + t) * 4096 + hw;
    xa[base] = a0;
    xa[base + 65536] = a1;
    xa[base + 131072] = a2;
    xa[base + 196608] = a3;
}

// ---------- grouped dilated 3D convs, 3 scales, weighted sum ----------
__global__ __launch_bounds__(256) void k_agg(const float* __restrict__ xa,
                                             const float* __restrict__ w1, const float* __restrict__ b1,
                                             const float* __restrict__ w2, const float* __restrict__ b2,
                                             const float* __restrict__ w3, const float* __restrict__ b3,
                                             const float* __restrict__ aw,
                                             float* __restrict__ agg)
{
    int gid = blockIdx.x * 256 + threadIdx.x;   // 524288 = 2*4*16*4096
    int hw = gid & 4095;
    int rest = gid >> 12;      // (b*4+g)*16+t
    int t = rest & 15;
    int g = (rest >> 4) & 3;
    int b = rest >> 6;
    int h = hw >> 6, w = hw & 63;
    const float* base = xa + ((size_t)(b * 4 + g) * 16) * 4096;
    const float* ws0 = w1 + g * 81;
    const float* ws1 = w2 + g * 81;
    const float* ws2 = w3 + g * 81;
    float acc0 = b1[g], acc1 = b2[g], acc2 = b3[g];
    for (int kd = 0; kd < 9; kd++) {
        int d = t + kd - 4;
        if (d < 0 || d > 15) continue;
        const float* fr = base + (size_t)d * 4096;
        #pragma unroll
        for (int kh = 0; kh < 3; kh++) {
            #pragma unroll
            for (int kw = 0; kw < 3; kw++) {
                int widx = kd * 9 + kh * 3 + kw;
                // scale 0: dil 1
                {
                    int yy = h + (kh - 1), xx = w + (kw - 1);
                    if (yy >= 0 && yy < 64 && xx >= 0 && xx < 64)
                        acc0 = fmaf(fr[yy * 64 + xx], ws0[widx], acc0);
                }
                // scale 1: dil 2
                {
                    int yy = h + (kh - 1) * 2, xx = w + (kw - 1) * 2;
                    if (yy >= 0 && yy < 64 && xx >= 0 && xx < 64)
                        acc1 = fmaf(fr[yy * 64 + xx], ws1[widx], acc1);
                }
                // scale 2: dil 3
                {
                    int yy = h + (kh - 1) * 3, xx = w + (kw - 1) * 3;
                    if (yy >= 0 && yy < 64 && xx >= 0 && xx < 64)
                        acc2 = fmaf(fr[yy * 64 + xx], ws2[widx], acc2);
                }
            }
        }
    }
    agg[gid] = acc0 * aw[0] + acc1 * aw[1] + acc2 * aw[2];
}

// ---------- conv1: 128->64 3x3 pad1 + ReLU.  input = cat([x(t), x(t+dir clamped)]) ----------
// grid: 2048 blocks = n(32) * tile(16) * co_chunk(4); block = 256 = 16x16 spatial
__global__ __launch_bounds__(256) void k_conv1(const float* __restrict__ x,
                                               const float* __restrict__ w1,
                                               const float* __restrict__ b1,
                                               float* __restrict__ hidden, int dir)
{
    int bid = blockIdx.x;
    int coc = bid & 3;
    int tile = (bid >> 2) & 15;
    int n = bid >> 6;
    int th0 = (tile >> 2) * 16;
    int tw0 = (tile & 3) * 16;
    int b = n >> 4, t = n & 15;
    int t2 = (dir > 0) ? min(t + 1, 15) : max(t - 1, 0);

    __shared__ __align__(16) float s_in[16][324];   // [ci][18*18]
    __shared__ __align__(16) float s_w[2304];       // [ci][k][co] = ci*144 + k*16 + co

    int tid = threadIdx.x;
    int ty = tid >> 4, tx = tid & 15;

    float acc[16];
    #pragma unroll
    for (int i = 0; i < 16; i++) acc[i] = b1[coc * 16 + i];

    for (int cc = 0; cc < 8; cc++) {
        __syncthreads();
        // stage 18x18 input tile for 16 input channels
        for (int idx = tid; idx < 16 * 324; idx += 256) {
            int ci = idx / 324;
            int p = idx - ci * 324;
            int iy = p / 18, ix = p - iy * 18;
            int gy = th0 - 1 + iy, gx = tw0 - 1 + ix;
            int cig = cc * 16 + ci;
            int src_c = (cig < 64) ? cig : (cig - 64);
            int src_t = (cig < 64) ? t : t2;
            float v = 0.f;
            if (gy >= 0 && gy < 64 && gx >= 0 && gx < 64)
                v = x[(((size_t)b * 64 + src_c) * 16 + src_t) * 4096 + gy * 64 + gx];
            s_in[ci][iy * 18 + ix] = v;
        }
        // stage weights [16ci][9k][16co]
        for (int idx = tid; idx < 2304; idx += 256) {
            int ci = idx / 144;
            int rem = idx - ci * 144;
            int k = rem >> 4;
            int co = rem & 15;
            s_w[idx] = w1[((size_t)(coc * 16 + co) * 128 + cc * 16 + ci) * 9 + k];
        }
        __syncthreads();
        for (int ci = 0; ci < 16; ci++) {
            #pragma unroll
            for (int k = 0; k < 9; k++) {
                int kh = k / 3, kw = k - kh * 3;
                float v = s_in[ci][(ty + kh) * 18 + tx + kw];
                const float* wp = &s_w[ci * 144 + k * 16];
                #pragma unroll
                for (int j = 0; j < 16; j += 4) {
                    float4 w4 = *(const float4*)(wp + j);
                    acc[j + 0] = fmaf(v, w4.x, acc[j + 0]);
                    acc[j + 1] = fmaf(v, w4.y, acc[j + 1]);
                    acc[j + 2] = fmaf(v, w4.z, acc[j + 2]);
                    acc[j + 3] = fmaf(v, w4.w, acc[j + 3]);
                }
            }
        }
    }
    int y = th0 + ty, xw = tw0 + tx;
    #pragma unroll
    for (int j = 0; j < 16; j++) {
        float r = acc[j] < 0.f ? 0.f : acc[j];
        hidden[((size_t)n * 64 + coc * 16 + j) * 4096 + y * 64 + xw] = r;
    }
}

// ---------- conv2: 64->6 3x3 pad1 (offsets) ----------
__global__ __launch_bounds__(256) void k_conv2(const float* __restrict__ hidden,
                                               const float* __restrict__ w2,
                                               const float* __restrict__ b2,
                                               float* __restrict__ off)
{
    int bid = blockIdx.x;              // 512 = n(32)*tile(16)
    int tile = bid & 15;
    int n = bid >> 4;
    int ty = threadIdx.x >> 4, tx = threadIdx.x & 15;
    int y = (tile >> 2) * 16 + ty, xw = (tile & 3) * 16 + tx;

    __shared__ float s_w[3456];        // [ci][k][co] = ci*54 + k*6 + co
    for (int idx = threadIdx.x; idx < 3456; idx += 256) {
        int ci = idx / 54;
        int rem = idx - ci * 54;
        int k = rem / 6;
        int co = rem - k * 6;
        s_w[idx] = w2[((size_t)co * 64 + ci) * 9 + k];
    }
    __syncthreads();

    float acc[6];
    #pragma unroll
    for (int j = 0; j < 6; j++) acc[j] = b2[j];

    for (int ci = 0; ci < 64; ci++) {
        const float* hp = &hidden[((size_t)n * 64 + ci) * 4096];
        const float* wp = &s_w[ci * 54];
        #pragma unroll
        for (int k = 0; k < 9; k++) {
            int kh = k / 3 - 1, kw = k - (k / 3) * 3 - 1;
            int yy = y + kh, xx = xw + kw;
            float v = (yy >= 0 && yy < 64 && xx >= 0 && xx < 64) ? hp[yy * 64 + xx] : 0.f;
            #pragma unroll
            for (int j = 0; j < 6; j++) acc[j] = fmaf(v, wp[k * 6 + j], acc[j]);
        }
    }
    #pragma unroll
    for (int j = 0; j < 6; j++)
        off[((size_t)n * 6 + j) * 4096 + y * 64 + xw] = acc[j];
}

// ---------- deformable correlation -> stats (avg,max,var) over 3 scales ----------
__global__ __launch_bounds__(256) void k_corr(const float* __restrict__ x,
                                              const float* __restrict__ off,
                                              float* __restrict__ stats, int dir)
{
    int gid = blockIdx.x * 256 + threadIdx.x;   // 131072
    int hw = gid & 4095;
    int n = gid >> 12;
    int b = n >> 4, t = n & 15;
    int t2 = (dir > 0) ? min(t + 1, 15) : max(t - 1, 0);
    int h = hw >> 6, w = hw & 63;

    const float* xf = x + (((size_t)b * 64) * 16 + t) * 4096;
    const float* yf = x + (((size_t)b * 64) * 16 + t2) * 4096;

    Samp sp[3];
    #pragma unroll
    for (int s = 0; s < 3; s++) {
        float ox = off[((size_t)n * 6 + 2 * s) * 4096 + hw];
        float oy = off[((size_t)n * 6 + 2 * s + 1) * 4096 + hw];
        sp[s] = make_samp(ox, oy, w, h);
    }

    float acc0 = 0.f, acc1 = 0.f, acc2 = 0.f;
    for (int c = 0; c < 64; c++) {
        const float* yp = yf + (size_t)c * 65536;
        float xv = xf[(size_t)c * 65536 + hw];
        float w0 = yp[sp[0].o0] * sp[0].w0 + yp[sp[0].o1] * sp[0].w1
                 + yp[sp[0].o2] * sp[0].w2 + yp[sp[0].o3] * sp[0].w3;
        float w1 = yp[sp[1].o0] * sp[1].w0 + yp[sp[1].o1] * sp[1].w1
                 + yp[sp[1].o2] * sp[1].w2 + yp[sp[1].o3] * sp[1].w3;
        float w2 = yp[sp[2].o0] * sp[2].w0 + yp[sp[2].o1] * sp[2].w1
                 + yp[sp[2].o2] * sp[2].w2 + yp[sp[2].o3] * sp[2].w3;
        acc0 = fmaf(xv, w0, acc0);
        acc1 = fmaf(xv, w1, acc1);
        acc2 = fmaf(xv, w2, acc2);
    }
    float c0 = acc0 * (1.0f / 64.0f);
    float c1 = acc1 * (1.0f / 64.0f);
    float c2 = acc2 * (1.0f / 64.0f);
    float avg = (c0 + c1 + c2) * (1.0f / 3.0f);
    float mx = fmaxf(c0, fmaxf(c1, c2));
    float d0 = c0 - avg, d1 = c1 - avg, d2 = c2 - avg;
    float var = (d0 * d0 + d1 * d1 + d2 * d2) * 0.5f;   // ddof=1
    stats[(size_t)n * 4096 + hw] = avg;
    stats[131072 + (size_t)n * 4096 + hw] = mx;
    stats[262144 + (size_t)n * 4096 + hw] = var;
}

// ---------- corr filter attention -> per-pixel feat multiplier A = sigmoid(avg*attn)-0.5 ----------
__global__ __launch_bounds__(256) void k_attn(const float* __restrict__ stats,
                                              const float* __restrict__ cfw1,
                                              const float* __restrict__ cfw2,
                                              float* __restrict__ A)
{
    int gid = blockIdx.x * 256 + threadIdx.x;   // 131072
    int hw = gid & 4095;
    int n = gid >> 12;
    int h = hw >> 6, w = hw & 63;
    const float* avg = stats + (size_t)n * 4096;
    const float* mx  = stats + 131072 + (size_t)n * 4096;
    const float* var = stats + 262144 + (size_t)n * 4096;
    float s = 0.f;
    #pragma unroll
    for (int k = 0; k < 9; k++) {
        int kh = k / 3 - 1, kw = k - (k / 3) * 3 - 1;
        int yy = h + kh, xx = w + kw;
        if (yy >= 0 && yy < 64 && xx >= 0 && xx < 64) {
            int p = yy * 64 + xx;
            s += avg[p] * cfw1[k] + mx[p] * cfw1[9 + k] + var[p] * cfw2[k];
        }
    }
    float attn = sigmoidf_(s);
    A[gid] = sigmoidf_(avg[hw] * attn) - 0.5f;
}

// ---------- final: warp both sides (scale-0 offsets), attn multipliers, long-term, output ----------
__global__ __launch_bounds__(256) void k_final(const float* __restrict__ x,
                                               const float* __restrict__ off_l,
                                               const float* __restrict__ off_r,
                                               const float* __restrict__ A_l,
                                               const float* __restrict__ A_r,
                                               const float* __restrict__ agg,
                                               const float* __restrict__ backw,
                                               const float* __restrict__ fusw,
                                               float* __restrict__ out)
{
    int gid = blockIdx.x * 256 + threadIdx.x;   // 131072
    int hw = gid & 4095;
    int n = gid >> 12;
    int b = n >> 4, t = n & 15;
    int tl = min(t + 1, 15), tr = max(t - 1, 0);
    int h = hw >> 6, w = hw & 63;

    float oxl = off_l[((size_t)n * 6 + 0) * 4096 + hw];
    float oyl = off_l[((size_t)n * 6 + 1) * 4096 + hw];
    float oxr = off_r[((size_t)n * 6 + 0) * 4096 + hw];
    float oyr = off_r[((size_t)n * 6 + 1) * 4096 + hw];
    Samp sl = make_samp(oxl, oyl, w, h);
    Samp sr = make_samp(oxr, oyr, w, h);

    const float* lf = x + (((size_t)b * 64) * 16 + tl) * 4096;
    const float* rf = x + (((size_t)b * 64) * 16 + tr) * 4096;

    float Al = A_l[gid] * fusw[0];
    float Ar = A_r[gid] * fusw[1];

    float ag0 = agg[((size_t)(b * 4 + 0) * 16 + t) * 4096 + hw];
    float ag1 = agg[((size_t)(b * 4 + 1) * 16 + t) * 4096 + hw];
    float ag2 = agg[((size_t)(b * 4 + 2) * 16 + t) * 4096 + hw];
    float ag3 = agg[((size_t)(b * 4 + 3) * 16 + t) * 4096 + hw];

    for (int c = 0; c < 64; c++) {
        const float* lp = lf + (size_t)c * 65536;
        const float* rp = rf + (size_t)c * 65536;
        float wl = lp[sl.o0] * sl.w0 + lp[sl.o1] * sl.w1 + lp[sl.o2] * sl.w2 + lp[sl.o3] * sl.w3;
        float wr = rp[sr.o0] * sr.w0 + rp[sr.o1] * sr.w1 + rp[sr.o2] * sr.w2 + rp[sr.o3] * sr.w3;
        float shortv = wl * Al + wr * Ar;
        float lt = sigmoidf_(ag0 * backw[c * 4 + 0] + ag1 * backw[c * 4 + 1]
                           + ag2 * backw[c * 4 + 2] + ag3 * backw[c * 4 + 3]) - 0.5f;
        out[(((size_t)b * 64 + c) * 16 + t) * 4096 + hw] = shortv * lt;
    }
}

extern "C" void kernel_launch(void* const* d_in, const int* in_sizes, int n_in,
                              void* d_out, int out_size, void* d_ws, size_t ws_size,
                              hipStream_t stream)
{
    const float* x     = (const float*)d_in[0];
    const float* lw1   = (const float*)d_in[1];
    const float* lb1   = (const float*)d_in[2];
    const float* lw2   = (const float*)d_in[3];
    const float* lb2   = (const float*)d_in[4];
    const float* rw1   = (const float*)d_in[5];
    const float* rb1   = (const float*)d_in[6];
    const float* rw2   = (const float*)d_in[7];
    const float* rb2   = (const float*)d_in[8];
    const float* cfw1  = (const float*)d_in[9];
    const float* cfw2  = (const float*)d_in[10];
    const float* downw = (const float*)d_in[11];
    const float* sa1w  = (const float*)d_in[12];
    const float* sa1b  = (const float*)d_in[13];
    const float* sa2w  = (const float*)d_in[14];
    const float* sa2b  = (const float*)d_in[15];
    const float* sa3w  = (const float*)d_in[16];
    const float* sa3b  = (const float*)d_in[17];
    const float* aggw  = (const float*)d_in[18];
    const float* backw = (const float*)d_in[19];
    const float* fusw  = (const float*)d_in[20];
    float* out = (float*)d_out;

    float* ws      = (float*)d_ws;
    float* x_agg   = ws;                    // 524288
    float* agg     = x_agg + 524288;        // 524288
    float* hidden  = agg + 524288;          // 8388608
    float* off_l   = hidden + 8388608;      // 786432
    float* off_r   = off_l + 786432;        // 786432
    float* stats_l = off_r + 786432;        // 393216
    float* stats_r = stats_l + 393216;      // 393216
    float* A_l     = stats_r + 393216;      // 131072
    float* A_r     = A_l + 131072;          // 131072

    k_down<<<512, 256, 0, stream>>>(x, downw, x_agg);
    k_agg<<<2048, 256, 0, stream>>>(x_agg, sa1w, sa1b, sa2w, sa2b, sa3w, sa3b, aggw, agg);

    // left branch
    k_conv1<<<2048, 256, 0, stream>>>(x, lw1, lb1, hidden, +1);
    k_conv2<<<512, 256, 0, stream>>>(hidden, lw2, lb2, off_l);
    k_corr<<<512, 256, 0, stream>>>(x, off_l, stats_l, +1);

    // right branch (reuses hidden)
    k_conv1<<<2048, 256, 0, stream>>>(x, rw1, rb1, hidden, -1);
    k_conv2<<<512, 256, 0, stream>>>(hidden, rw2, rb2, off_r);
    k_corr<<<512, 256, 0, stream>>>(x, off_r, stats_r, -1);

    k_attn<<<512, 256, 0, stream>>>(stats_l, cfw1, cfw2, A_l);
    k_attn<<<512, 256, 0, stream>>>(stats_r, cfw1, cfw2, A_r);

    k_final<<<512, 256, 0, stream>>>(x, off_l, off_r, A_l, A_r, agg, backw, fusw, out);
}

// Round 2
// 714.621 us; speedup vs baseline: 1.5847x; 1.5847x over previous
//
#include <hip/hip_runtime.h>
#include <hip/hip_bf16.h>
#include <math.h>

// Layout constants: B=2, C=64, T=16, H=W=64, S=3, r=4
// x index: ((b*64+c)*16+t)*4096 + h*64+w ; frame n in [0,32): b=n>>4, t=n&15

typedef __attribute__((ext_vector_type(8))) short short8v;
typedef __attribute__((ext_vector_type(4))) short short4v;
typedef __attribute__((ext_vector_type(4))) float f32x4;

__device__ __forceinline__ float sigmoidf_(float v) {
    return 1.0f / (1.0f + expf(-v));
}

// Bilinear sample setup matching reference grid_sample semantics.
struct Samp { int o0, o1, o2, o3; float w0, w1, w2, w3; };

__device__ __forceinline__ Samp make_samp(float ox, float oy, int w, int h) {
    float bx = (2.0f * (float)w) / 63.0f - 1.0f;
    float by = (2.0f * (float)h) / 63.0f - 1.0f;
    float vx = bx + ox / 63.0f;
    float vy = by + oy / 63.0f;
    float gx = ((vx + 1.0f) * 64.0f - 1.0f) * 0.5f;
    float gy = ((vy + 1.0f) * 64.0f - 1.0f) * 0.5f;
    float fx = floorf(gx), fy = floorf(gy);
    float wx = gx - fx, wy = gy - fy;
    int x0 = (int)fx, y0 = (int)fy;
    int x1 = x0 + 1, y1 = y0 + 1;
    bool vx0 = (x0 >= 0) && (x0 < 64), vx1 = (x1 >= 0) && (x1 < 64);
    bool vy0 = (y0 >= 0) && (y0 < 64), vy1 = (y1 >= 0) && (y1 < 64);
    int cx0 = min(max(x0, 0), 63), cx1 = min(max(x1, 0), 63);
    int cy0 = min(max(y0, 0), 63), cy1 = min(max(y1, 0), 63);
    Samp s;
    s.o0 = cy0 * 64 + cx0; s.w0 = (1.0f - wx) * (1.0f - wy) * ((vx0 && vy0) ? 1.0f : 0.0f);
    s.o1 = cy0 * 64 + cx1; s.w1 = wx * (1.0f - wy) * ((vx1 && vy0) ? 1.0f : 0.0f);
    s.o2 = cy1 * 64 + cx0; s.w2 = (1.0f - wx) * wy * ((vx0 && vy1) ? 1.0f : 0.0f);
    s.o3 = cy1 * 64 + cx1; s.w3 = wx * wy * ((vx1 && vy1) ? 1.0f : 0.0f);
    return s;
}

// ---------- prep: x (B,64,T,H,W) fp32 -> xT bf16 [n][h][w' 0..65][c 0..63], w'=w+1, cols 0/65 zero ----------
__global__ __launch_bounds__(256) void k_prep_x(const float* __restrict__ x,
                                                __hip_bfloat16* __restrict__ xT)
{
    int bid = blockIdx.x;          // 2048 = n*64 + h
    int h = bid & 63;
    int n = bid >> 6;
    int b = n >> 4, t = n & 15;
    __shared__ float s[64][65];
    int tid = threadIdx.x;
    for (int idx = tid; idx < 4096; idx += 256) {
        int c = idx >> 6, w = idx & 63;
        s[c][w] = x[(((size_t)b * 64 + c) * 16 + t) * 4096 + h * 64 + w];
    }
    __syncthreads();
    __hip_bfloat16* op = xT + ((size_t)n * 64 + h) * (66 * 64);
    for (int idx = tid; idx < 66 * 64; idx += 256) {
        int wp = idx >> 6, c = idx & 63;
        float v = (wp == 0 || wp == 65) ? 0.f : s[c][wp - 1];
        op[idx] = __float2bfloat16(v);
    }
}

// ---------- prep: weights fp32 [co 64][ci 128][3][3] -> Wb bf16 [side][tap 9][co 64][ci 128] ----------
__global__ __launch_bounds__(256) void k_prep_w(const float* __restrict__ wl,
                                                const float* __restrict__ wr,
                                                __hip_bfloat16* __restrict__ Wb)
{
    int idx = blockIdx.x * 256 + threadIdx.x;    // 147456 total
    int side = (idx >= 73728) ? 1 : 0;
    int i = idx - side * 73728;
    int ci = i & 127;
    int co = (i >> 7) & 63;
    int tap = i >> 13;
    const float* w = side ? wr : wl;
    Wb[idx] = __float2bfloat16(w[((size_t)co * 128 + ci) * 9 + tap]);
}

// ---------- conv1 via MFMA: 128->64 3x3 pad1 + ReLU, bf16 in / bf16 out ----------
// block = one (frame n, row r): M=64 px, N=64 co, K=1152. 4 waves, 2x2 wave tiling.
__global__ __launch_bounds__(256) void k_conv1_mfma(const __hip_bfloat16* __restrict__ xT,
                                                    const __hip_bfloat16* __restrict__ Wb,
                                                    const float* __restrict__ b1,
                                                    __hip_bfloat16* __restrict__ hidden,
                                                    int dir)
{
    int bid = blockIdx.x;          // 2048 = n*64 + r
    int r = bid & 63;
    int n = bid >> 6;
    int t = n & 15, b = n >> 4;
    int t2 = (dir > 0) ? min(t + 1, 15) : max(t - 1, 0);
    int n2 = b * 16 + t2;

    int tid = threadIdx.x;
    int wv = tid >> 6;
    int lane = tid & 63;
    int m0 = (wv & 1) * 32;        // px base of wave
    int n0 = (wv >> 1) * 32;       // co base of wave
    int lr = lane & 15;            // A row (px) / B col (co) / D col (co)
    int lk = (lane >> 4) << 3;     // k offset within 32-slice: 0,8,16,24

    f32x4 acc[2][2];
    #pragma unroll
    for (int ni = 0; ni < 2; ni++) {
        float bb = b1[n0 + ni * 16 + lr];
        acc[0][ni] = (f32x4){bb, bb, bb, bb};
        acc[1][ni] = (f32x4){bb, bb, bb, bb};
    }

    const __hip_bfloat16* fA0 = xT + (size_t)n  * (64 * 66 * 64);
    const __hip_bfloat16* fA1 = xT + (size_t)n2 * (64 * 66 * 64);

    for (int tap = 0; tap < 9; tap++) {
        int kh = tap / 3, kw = tap - kh * 3;
        int rr = r + kh - 1;
        if (rr < 0 || rr > 63) continue;       // zero-pad rows: whole tap contributes 0
        int arow = (rr * 66 + (m0 + lr + kw)) * 64 + lk;   // col' = px + kw in [0,65] (padded)
        const __hip_bfloat16* a00 = fA0 + arow;            // khalf=0 (frame t),  mi=0
        const __hip_bfloat16* a01 = a00 + 16 * 64;         // mi=1
        const __hip_bfloat16* a10 = fA1 + arow;            // khalf=1 (neighbor)
        const __hip_bfloat16* a11 = a10 + 16 * 64;
        const __hip_bfloat16* bw0 = Wb + (((size_t)tap * 64 + n0 + lr) * 128 + lk);
        const __hip_bfloat16* bw1 = bw0 + 16 * 128;
        #pragma unroll
        for (int khalf = 0; khalf < 2; khalf++) {
            #pragma unroll
            for (int ks = 0; ks < 2; ks++) {
                int aoff = ks * 32;
                int boff = khalf * 64 + ks * 32;
                short8v a0 = *(const short8v*)((khalf ? a10 : a00) + aoff);
                short8v a1 = *(const short8v*)((khalf ? a11 : a01) + aoff);
                short8v v0 = *(const short8v*)(bw0 + boff);
                short8v v1 = *(const short8v*)(bw1 + boff);
                acc[0][0] = __builtin_amdgcn_mfma_f32_16x16x32_bf16(a0, v0, acc[0][0], 0, 0, 0);
                acc[1][0] = __builtin_amdgcn_mfma_f32_16x16x32_bf16(a1, v0, acc[1][0], 0, 0, 0);
                acc[0][1] = __builtin_amdgcn_mfma_f32_16x16x32_bf16(a0, v1, acc[0][1], 0, 0, 0);
                acc[1][1] = __builtin_amdgcn_mfma_f32_16x16x32_bf16(a1, v1, acc[1][1], 0, 0, 0);
            }
        }
    }

    // D layout: col(co_local)=lane&15, row(px_local)=(lane>>4)*4+j
    int pxb = m0 + ((lane >> 4) << 2);
    #pragma unroll
    for (int mi = 0; mi < 2; mi++) {
        #pragma unroll
        for (int ni = 0; ni < 2; ni++) {
            int co = n0 + ni * 16 + lr;
            __hip_bfloat16* hp = hidden + (((size_t)n * 64 + co) * 4096 + r * 64 + pxb + mi * 16);
            union { short4v v; __hip_bfloat16 bh[4]; } u;
            #pragma unroll
            for (int j = 0; j < 4; j++) {
                float vv = acc[mi][ni][j];
                vv = vv < 0.f ? 0.f : vv;
                u.bh[j] = __float2bfloat16(vv);
            }
            *(short4v*)hp = u.v;
        }
    }
}

// ---------- 1x1x1 down conv: x (B,64,T,H,W) -> x_agg (B,4,T,H,W) ----------
__global__ __launch_bounds__(256) void k_down(const float* __restrict__ x,
                                              const float* __restrict__ dw,
                                              float* __restrict__ xa)
{
    int gid = blockIdx.x * 256 + threadIdx.x;   // 131072 = 32*4096
    int hw = gid & 4095;
    int bt = gid >> 12;
    int b = bt >> 4, t = bt & 15;
    float a0 = 0.f, a1 = 0.f, a2 = 0.f, a3 = 0.f;
    const float* xp = x + (((size_t)b * 64) * 16 + t) * 4096 + hw;
    for (int c = 0; c < 64; c++) {
        float v = xp[(size_t)c * 65536];
        a0 = fmaf(v, dw[c], a0);
        a1 = fmaf(v, dw[64 + c], a1);
        a2 = fmaf(v, dw[128 + c], a2);
        a3 = fmaf(v, dw[192 + c], a3);
    }
    size_t base = (((size_t)b * 4) * 16 + t) * 4096 + hw;
    xa[base] = a0;
    xa[base + 65536] = a1;
    xa[base + 131072] = a2;
    xa[base + 196608] = a3;
}

// ---------- grouped dilated 3D convs, 3 scales, weighted sum ----------
__global__ __launch_bounds__(256) void k_agg(const float* __restrict__ xa,
                                             const float* __restrict__ w1, const float* __restrict__ b1,
                                             const float* __restrict__ w2, const float* __restrict__ b2,
                                             const float* __restrict__ w3, const float* __restrict__ b3,
                                             const float* __restrict__ aw,
                                             float* __restrict__ agg)
{
    int gid = blockIdx.x * 256 + threadIdx.x;   // 524288
    int hw = gid & 4095;
    int rest = gid >> 12;      // (b*4+g)*16+t
    int t = rest & 15;
    int g = (rest >> 4) & 3;
    int b = rest >> 6;
    int h = hw >> 6, w = hw & 63;
    const float* base = xa + ((size_t)(b * 4 + g) * 16) * 4096;
    const float* ws0 = w1 + g * 81;
    const float* ws1 = w2 + g * 81;
    const float* ws2 = w3 + g * 81;
    float acc0 = b1[g], acc1 = b2[g], acc2 = b3[g];
    for (int kd = 0; kd < 9; kd++) {
        int d = t + kd - 4;
        if (d < 0 || d > 15) continue;
        const float* fr = base + (size_t)d * 4096;
        #pragma unroll
        for (int kh = 0; kh < 3; kh++) {
            #pragma unroll
            for (int kw = 0; kw < 3; kw++) {
                int widx = kd * 9 + kh * 3 + kw;
                {
                    int yy = h + (kh - 1), xx = w + (kw - 1);
                    if (yy >= 0 && yy < 64 && xx >= 0 && xx < 64)
                        acc0 = fmaf(fr[yy * 64 + xx], ws0[widx], acc0);
                }
                {
                    int yy = h + (kh - 1) * 2, xx = w + (kw - 1) * 2;
                    if (yy >= 0 && yy < 64 && xx >= 0 && xx < 64)
                        acc1 = fmaf(fr[yy * 64 + xx], ws1[widx], acc1);
                }
                {
                    int yy = h + (kh - 1) * 3, xx = w + (kw - 1) * 3;
                    if (yy >= 0 && yy < 64 && xx >= 0 && xx < 64)
                        acc2 = fmaf(fr[yy * 64 + xx], ws2[widx], acc2);
                }
            }
        }
    }
    agg[gid] = acc0 * aw[0] + acc1 * aw[1] + acc2 * aw[2];
}

// ---------- conv2: 64->6 3x3 pad1 (offsets), bf16 hidden in, fp32 out ----------
__global__ __launch_bounds__(256) void k_conv2(const __hip_bfloat16* __restrict__ hidden,
                                               const float* __restrict__ w2,
                                               const float* __restrict__ b2,
                                               float* __restrict__ off)
{
    int bid = blockIdx.x;              // 512 = n(32)*tile(16)
    int tile = bid & 15;
    int n = bid >> 4;
    int ty = threadIdx.x >> 4, tx = threadIdx.x & 15;
    int y = (tile >> 2) * 16 + ty, xw = (tile & 3) * 16 + tx;

    __shared__ float s_w[3456];        // [ci][k][co] = ci*54 + k*6 + co
    for (int idx = threadIdx.x; idx < 3456; idx += 256) {
        int ci = idx / 54;
        int rem = idx - ci * 54;
        int k = rem / 6;
        int co = rem - k * 6;
        s_w[idx] = w2[((size_t)co * 64 + ci) * 9 + k];
    }
    __syncthreads();

    float acc[6];
    #pragma unroll
    for (int j = 0; j < 6; j++) acc[j] = b2[j];

    for (int ci = 0; ci < 64; ci++) {
        const __hip_bfloat16* hp = &hidden[((size_t)n * 64 + ci) * 4096];
        const float* wp = &s_w[ci * 54];
        #pragma unroll
        for (int k = 0; k < 9; k++) {
            int kh = k / 3 - 1, kw = k - (k / 3) * 3 - 1;
            int yy = y + kh, xx = xw + kw;
            float v = (yy >= 0 && yy < 64 && xx >= 0 && xx < 64) ? __bfloat162float(hp[yy * 64 + xx]) : 0.f;
            #pragma unroll
            for (int j = 0; j < 6; j++) acc[j] = fmaf(v, wp[k * 6 + j], acc[j]);
        }
    }
    #pragma unroll
    for (int j = 0; j < 6; j++)
        off[((size_t)n * 6 + j) * 4096 + y * 64 + xw] = acc[j];
}

// ---------- deformable correlation -> stats (avg,max,var) over 3 scales ----------
__global__ __launch_bounds__(256) void k_corr(const float* __restrict__ x,
                                              const float* __restrict__ off,
                                              float* __restrict__ stats, int dir)
{
    int gid = blockIdx.x * 256 + threadIdx.x;   // 131072
    int hw = gid & 4095;
    int n = gid >> 12;
    int b = n >> 4, t = n & 15;
    int t2 = (dir > 0) ? min(t + 1, 15) : max(t - 1, 0);
    int h = hw >> 6, w = hw & 63;

    const float* xf = x + (((size_t)b * 64) * 16 + t) * 4096;
    const float* yf = x + (((size_t)b * 64) * 16 + t2) * 4096;

    Samp sp[3];
    #pragma unroll
    for (int s = 0; s < 3; s++) {
        float ox = off[((size_t)n * 6 + 2 * s) * 4096 + hw];
        float oy = off[((size_t)n * 6 + 2 * s + 1) * 4096 + hw];
        sp[s] = make_samp(ox, oy, w, h);
    }

    float acc0 = 0.f, acc1 = 0.f, acc2 = 0.f;
    for (int c = 0; c < 64; c++) {
        const float* yp = yf + (size_t)c * 65536;
        float xv = xf[(size_t)c * 65536 + hw];
        float w0 = yp[sp[0].o0] * sp[0].w0 + yp[sp[0].o1] * sp[0].w1
                 + yp[sp[0].o2] * sp[0].w2 + yp[sp[0].o3] * sp[0].w3;
        float w1 = yp[sp[1].o0] * sp[1].w0 + yp[sp[1].o1] * sp[1].w1
                 + yp[sp[1].o2] * sp[1].w2 + yp[sp[1].o3] * sp[1].w3;
        float w2 = yp[sp[2].o0] * sp[2].w0 + yp[sp[2].o1] * sp[2].w1
                 + yp[sp[2].o2] * sp[2].w2 + yp[sp[2].o3] * sp[2].w3;
        acc0 = fmaf(xv, w0, acc0);
        acc1 = fmaf(xv, w1, acc1);
        acc2 = fmaf(xv, w2, acc2);
    }
    float c0 = acc0 * (1.0f / 64.0f);
    float c1 = acc1 * (1.0f / 64.0f);
    float c2 = acc2 * (1.0f / 64.0f);
    float avg = (c0 + c1 + c2) * (1.0f / 3.0f);
    float mx = fmaxf(c0, fmaxf(c1, c2));
    float d0 = c0 - avg, d1 = c1 - avg, d2 = c2 - avg;
    float var = (d0 * d0 + d1 * d1 + d2 * d2) * 0.5f;   // ddof=1
    stats[(size_t)n * 4096 + hw] = avg;
    stats[131072 + (size_t)n * 4096 + hw] = mx;
    stats[262144 + (size_t)n * 4096 + hw] = var;
}

// ---------- per-pixel feat multiplier A = sigmoid(avg*attn)-0.5 (inline in final) ----------
__device__ __forceinline__ float attn_val(const float* __restrict__ stats, int n, int hw,
                                          const float* __restrict__ cfw1,
                                          const float* __restrict__ cfw2)
{
    int h = hw >> 6, w = hw & 63;
    const float* avg = stats + (size_t)n * 4096;
    const float* mx  = stats + 131072 + (size_t)n * 4096;
    const float* var = stats + 262144 + (size_t)n * 4096;
    float s = 0.f;
    #pragma unroll
    for (int k = 0; k < 9; k++) {
        int kh = k / 3 - 1, kw = k - (k / 3) * 3 - 1;
        int yy = h + kh, xx = w + kw;
        if (yy >= 0 && yy < 64 && xx >= 0 && xx < 64) {
            int p = yy * 64 + xx;
            s += avg[p] * cfw1[k] + mx[p] * cfw1[9 + k] + var[p] * cfw2[k];
        }
    }
    float attn = sigmoidf_(s);
    return sigmoidf_(avg[hw] * attn) - 0.5f;
}

// ---------- final: warp both sides (scale-0 offsets), attn multipliers, long-term, output ----------
__global__ __launch_bounds__(256) void k_final(const float* __restrict__ x,
                                               const float* __restrict__ off_l,
                                               const float* __restrict__ off_r,
                                               const float* __restrict__ stats_l,
                                               const float* __restrict__ stats_r,
                                               const float* __restrict__ cfw1,
                                               const float* __restrict__ cfw2,
                                               const float* __restrict__ agg,
                                               const float* __restrict__ backw,
                                               const float* __restrict__ fusw,
                                               float* __restrict__ out)
{
    int gid = blockIdx.x * 256 + threadIdx.x;   // 131072
    int hw = gid & 4095;
    int n = gid >> 12;
    int b = n >> 4, t = n & 15;
    int tl = min(t + 1, 15), tr = max(t - 1, 0);
    int h = hw >> 6, w = hw & 63;

    float oxl = off_l[((size_t)n * 6 + 0) * 4096 + hw];
    float oyl = off_l[((size_t)n * 6 + 1) * 4096 + hw];
    float oxr = off_r[((size_t)n * 6 + 0) * 4096 + hw];
    float oyr = off_r[((size_t)n * 6 + 1) * 4096 + hw];
    Samp sl = make_samp(oxl, oyl, w, h);
    Samp sr = make_samp(oxr, oyr, w, h);

    const float* lf = x + (((size_t)b * 64) * 16 + tl) * 4096;
    const float* rf = x + (((size_t)b * 64) * 16 + tr) * 4096;

    float Al = attn_val(stats_l, n, hw, cfw1, cfw2) * fusw[0];
    float Ar = attn_val(stats_r, n, hw, cfw1, cfw2) * fusw[1];

    float ag0 = agg[((size_t)(b * 4 + 0) * 16 + t) * 4096 + hw];
    float ag1 = agg[((size_t)(b * 4 + 1) * 16 + t) * 4096 + hw];
    float ag2 = agg[((size_t)(b * 4 + 2) * 16 + t) * 4096 + hw];
    float ag3 = agg[((size_t)(b * 4 + 3) * 16 + t) * 4096 + hw];

    for (int c = 0; c < 64; c++) {
        const float* lp = lf + (size_t)c * 65536;
        const float* rp = rf + (size_t)c * 65536;
        float wl = lp[sl.o0] * sl.w0 + lp[sl.o1] * sl.w1 + lp[sl.o2] * sl.w2 + lp[sl.o3] * sl.w3;
        float wr = rp[sr.o0] * sr.w0 + rp[sr.o1] * sr.w1 + rp[sr.o2] * sr.w2 + rp[sr.o3] * sr.w3;
        float shortv = wl * Al + wr * Ar;
        float lt = sigmoidf_(ag0 * backw[c * 4 + 0] + ag1 * backw[c * 4 + 1]
                           + ag2 * backw[c * 4 + 2] + ag3 * backw[c * 4 + 3]) - 0.5f;
        out[(((size_t)b * 64 + c) * 16 + t) * 4096 + hw] = shortv * lt;
    }
}

extern "C" void kernel_launch(void* const* d_in, const int* in_sizes, int n_in,
                              void* d_out, int out_size, void* d_ws, size_t ws_size,
                              hipStream_t stream)
{
    const float* x     = (const float*)d_in[0];
    const float* lw1   = (const float*)d_in[1];
    const float* lb1   = (const float*)d_in[2];
    const float* lw2   = (const float*)d_in[3];
    const float* lb2   = (const float*)d_in[4];
    const float* rw1   = (const float*)d_in[5];
    const float* rb1   = (const float*)d_in[6];
    const float* rw2   = (const float*)d_in[7];
    const float* rb2   = (const float*)d_in[8];
    const float* cfw1  = (const float*)d_in[9];
    const float* cfw2  = (const float*)d_in[10];
    const float* downw = (const float*)d_in[11];
    const float* sa1w  = (const float*)d_in[12];
    const float* sa1b  = (const float*)d_in[13];
    const float* sa2w  = (const float*)d_in[14];
    const float* sa2b  = (const float*)d_in[15];
    const float* sa3w  = (const float*)d_in[16];
    const float* sa3b  = (const float*)d_in[17];
    const float* aggw  = (const float*)d_in[18];
    const float* backw = (const float*)d_in[19];
    const float* fusw  = (const float*)d_in[20];
    float* out = (float*)d_out;

    // workspace layout (48.0 MB total, <= round-1's 48.25 MB which passed)
    float* ws      = (float*)d_ws;
    float* x_agg   = ws;                    // 524288 f
    float* agg     = x_agg + 524288;        // 524288 f
    float* off_l   = agg + 524288;          // 786432 f
    float* off_r   = off_l + 786432;        // 786432 f
    float* stats_l = off_r + 786432;        // 393216 f
    float* stats_r = stats_l + 393216;      // 393216 f
    __hip_bfloat16* hidden = (__hip_bfloat16*)(stats_r + 393216);  // 8388608 bf16
    __hip_bfloat16* xT     = hidden + 8388608;                     // 8650752 bf16
    __hip_bfloat16* Wb     = xT + 8650752;                         // 147456 bf16 (both sides)

    k_prep_x<<<2048, 256, 0, stream>>>(x, xT);
    k_prep_w<<<576, 256, 0, stream>>>(lw1, rw1, Wb);

    k_down<<<512, 256, 0, stream>>>(x, downw, x_agg);
    k_agg<<<2048, 256, 0, stream>>>(x_agg, sa1w, sa1b, sa2w, sa2b, sa3w, sa3b, aggw, agg);

    // left branch
    k_conv1_mfma<<<2048, 256, 0, stream>>>(xT, Wb, lb1, hidden, +1);
    k_conv2<<<512, 256, 0, stream>>>(hidden, lw2, lb2, off_l);
    k_corr<<<512, 256, 0, stream>>>(x, off_l, stats_l, +1);

    // right branch (reuses hidden)
    k_conv1_mfma<<<2048, 256, 0, stream>>>(xT, Wb + 73728, rb1, hidden, -1);
    k_conv2<<<512, 256, 0, stream>>>(hidden, rw2, rb2, off_r);
    k_corr<<<512, 256, 0, stream>>>(x, off_r, stats_r, -1);

    k_final<<<512, 256, 0, stream>>>(x, off_l, off_r, stats_l, stats_r, cfw1, cfw2,
                                     agg, backw, fusw, out);
}

// Round 3
// 423.652 us; speedup vs baseline: 2.6730x; 1.6868x over previous
//
#include <hip/hip_runtime.h>
#include <hip/hip_bf16.h>
#include <math.h>

// Layout constants: B=2, C=64, T=16, H=W=64, S=3, r=4
// x: ((b*64+c)*16+t)*4096 + h*64+w ; frame n in [0,32): b=n>>4, t=n&15
// xT bf16: [n][h 0..63][w' 0..65][c 0..63], w'=w+1, cols 0/65 zero. frame stride 270336, row stride 4224
// hidden bf16: [n][r 0..63][px' 0..65][co 0..63], pad cols zero. frame stride 270336, row stride 4224

typedef __attribute__((ext_vector_type(8))) short short8v;
typedef __attribute__((ext_vector_type(4))) float f32x4;

__device__ __forceinline__ float sigmoidf_(float v) {
    return 1.0f / (1.0f + expf(-v));
}

__device__ __forceinline__ float bf2f(short s) {
    union { unsigned u; float f; } z;
    z.u = ((unsigned)(unsigned short)s) << 16;
    return z.f;
}

// Bilinear sample setup matching reference grid_sample semantics; offsets in xT/channel-last coords.
struct Samp { int o0, o1, o2, o3; float w0, w1, w2, w3; };

__device__ __forceinline__ Samp make_samp(float ox, float oy, int w, int h) {
    float bx = (2.0f * (float)w) / 63.0f - 1.0f;
    float by = (2.0f * (float)h) / 63.0f - 1.0f;
    float vx = bx + ox / 63.0f;
    float vy = by + oy / 63.0f;
    float gx = ((vx + 1.0f) * 64.0f - 1.0f) * 0.5f;
    float gy = ((vy + 1.0f) * 64.0f - 1.0f) * 0.5f;
    float fx = floorf(gx), fy = floorf(gy);
    float wx = gx - fx, wy = gy - fy;
    int x0 = (int)fx, y0 = (int)fy;
    int x1 = x0 + 1, y1 = y0 + 1;
    bool vx0 = (x0 >= 0) && (x0 < 64), vx1 = (x1 >= 0) && (x1 < 64);
    bool vy0 = (y0 >= 0) && (y0 < 64), vy1 = (y1 >= 0) && (y1 < 64);
    int cx0 = min(max(x0, 0), 63), cx1 = min(max(x1, 0), 63);
    int cy0 = min(max(y0, 0), 63), cy1 = min(max(y1, 0), 63);
    Samp s;
    s.o0 = cy0 * 4224 + (cx0 + 1) * 64; s.w0 = (1.0f - wx) * (1.0f - wy) * ((vx0 && vy0) ? 1.0f : 0.0f);
    s.o1 = cy0 * 4224 + (cx1 + 1) * 64; s.w1 = wx * (1.0f - wy) * ((vx1 && vy0) ? 1.0f : 0.0f);
    s.o2 = cy1 * 4224 + (cx0 + 1) * 64; s.w2 = (1.0f - wx) * wy * ((vx0 && vy1) ? 1.0f : 0.0f);
    s.o3 = cy1 * 4224 + (cx1 + 1) * 64; s.w3 = wx * wy * ((vx1 && vy1) ? 1.0f : 0.0f);
    return s;
}

// ---------- prep: x fp32 -> xT bf16 channel-last padded ----------
__global__ __launch_bounds__(256) void k_prep_x(const float* __restrict__ x,
                                                __hip_bfloat16* __restrict__ xT)
{
    int bid = blockIdx.x;          // 2048 = n*64 + h
    int h = bid & 63;
    int n = bid >> 6;
    int b = n >> 4, t = n & 15;
    __shared__ float s[64][65];
    int tid = threadIdx.x;
    for (int idx = tid; idx < 4096; idx += 256) {
        int c = idx >> 6, w = idx & 63;
        s[c][w] = x[(((size_t)b * 64 + c) * 16 + t) * 4096 + h * 64 + w];
    }
    __syncthreads();
    __hip_bfloat16* op = xT + ((size_t)n * 64 + h) * 4224;
    for (int idx = tid; idx < 4224; idx += 256) {
        int wp = idx >> 6, c = idx & 63;
        float v = (wp == 0 || wp == 65) ? 0.f : s[c][wp - 1];
        op[idx] = __float2bfloat16(v);
    }
}

// ---------- prep: conv1 weights, zero-row, conv2 weights (padded co16), hidden pad cols ----------
// Wmisc layout: [Wb 147456][zrow 4224][W2b_L 9216][W2b_R 9216]
__global__ __launch_bounds__(256) void k_prep_w(const float* __restrict__ wl1,
                                                const float* __restrict__ wr1,
                                                const float* __restrict__ wl2,
                                                const float* __restrict__ wr2,
                                                __hip_bfloat16* __restrict__ Wmisc,
                                                __hip_bfloat16* __restrict__ hidden)
{
    int idx = blockIdx.x * 256 + threadIdx.x;    // 1689*256 = 432384, used 432256
    if (idx < 147456) {
        // conv1: [side][tap 9][co 64][ci 128]
        int side = (idx >= 73728) ? 1 : 0;
        int i = idx - side * 73728;
        int ci = i & 127;
        int co = (i >> 7) & 63;
        int tap = i >> 13;
        const float* w = side ? wr1 : wl1;
        Wmisc[idx] = __float2bfloat16(w[((size_t)co * 128 + ci) * 9 + tap]);
    } else if (idx < 151680) {
        Wmisc[idx] = __float2bfloat16(0.f);      // zero row (4224)
    } else if (idx < 170112) {
        // conv2: [side][tap 9][co 16 pad][ci 64]
        int i2 = idx - 151680;
        int side = i2 / 9216;
        int j = i2 - side * 9216;
        int tap = j >> 10;
        int rem = j & 1023;
        int co = rem >> 6;
        int ci = rem & 63;
        const float* w = side ? wr2 : wl2;
        float v = (co < 6) ? w[((size_t)co * 64 + ci) * 9 + tap] : 0.f;
        Wmisc[idx] = __float2bfloat16(v);
    } else if (idx < 432256) {
        // hidden pad columns px' in {0,65}
        int i3 = idx - 170112;                   // 262144 = 32*64*2*64
        int co = i3 & 63;
        int sel = (i3 >> 6) & 1;
        int rr = (i3 >> 7) & 63;
        int nn = i3 >> 13;
        hidden[((size_t)(nn * 64 + rr) * 66 + (sel ? 65 : 0)) * 64 + co] = __float2bfloat16(0.f);
    }
}

// ---------- conv1 via MFMA: 128->64 3x3 pad1 + ReLU, branch-free zero-row ----------
// grid 1024 = n(32)*rowpair(32); 4 waves = row(2) x m0(2); wave tile M=32 x N=64
__global__ __launch_bounds__(256) void k_conv1_mfma(const __hip_bfloat16* __restrict__ xT,
                                                    const __hip_bfloat16* __restrict__ Wb,
                                                    const __hip_bfloat16* __restrict__ zrow,
                                                    const float* __restrict__ b1,
                                                    __hip_bfloat16* __restrict__ hidden,
                                                    int dir)
{
    int bid = blockIdx.x;
    int rp = bid & 31;
    int n = bid >> 5;
    int b = n >> 4, t = n & 15;
    int t2 = (dir > 0) ? min(t + 1, 15) : max(t - 1, 0);
    int n2 = b * 16 + t2;

    int tid = threadIdx.x;
    int wv = tid >> 6;
    int lane = tid & 63;
    int r = rp * 2 + (wv & 1);
    int m0 = (wv >> 1) * 32;
    int lr = lane & 15;
    int lk = (lane >> 4) << 3;

    const __hip_bfloat16* fA0 = xT + (size_t)n * 270336;
    const __hip_bfloat16* fA1 = xT + (size_t)n2 * 270336;

    f32x4 acc[2][4];
    #pragma unroll
    for (int ni = 0; ni < 4; ni++) {
        float bb = b1[ni * 16 + lr];
        acc[0][ni] = (f32x4){bb, bb, bb, bb};
        acc[1][ni] = (f32x4){bb, bb, bb, bb};
    }

    #pragma unroll
    for (int tap = 0; tap < 9; tap++) {
        const int kh = tap / 3, kw = tap - (tap / 3) * 3;
        int rr = r + kh - 1;
        bool ok = (rr >= 0) && (rr < 64);
        const __hip_bfloat16* r0 = ok ? (fA0 + rr * 4224) : zrow;
        const __hip_bfloat16* r1 = ok ? (fA1 + rr * 4224) : zrow;
        int abase = (m0 + lr + kw) * 64 + lk;

        short8v a[2][2][2];   // [mi][khalf][ks]
        #pragma unroll
        for (int mi = 0; mi < 2; mi++) {
            #pragma unroll
            for (int ks = 0; ks < 2; ks++) {
                a[mi][0][ks] = *(const short8v*)(r0 + abase + mi * 1024 + ks * 32);
                a[mi][1][ks] = *(const short8v*)(r1 + abase + mi * 1024 + ks * 32);
            }
        }
        const __hip_bfloat16* bw = Wb + ((size_t)tap * 64 + lr) * 128 + lk;
        #pragma unroll
        for (int ni = 0; ni < 4; ni++) {
            short8v b00 = *(const short8v*)(bw + ni * 2048);
            short8v b01 = *(const short8v*)(bw + ni * 2048 + 32);
            short8v b10 = *(const short8v*)(bw + ni * 2048 + 64);
            short8v b11 = *(const short8v*)(bw + ni * 2048 + 96);
            #pragma unroll
            for (int mi = 0; mi < 2; mi++) {
                acc[mi][ni] = __builtin_amdgcn_mfma_f32_16x16x32_bf16(a[mi][0][0], b00, acc[mi][ni], 0, 0, 0);
                acc[mi][ni] = __builtin_amdgcn_mfma_f32_16x16x32_bf16(a[mi][0][1], b01, acc[mi][ni], 0, 0, 0);
                acc[mi][ni] = __builtin_amdgcn_mfma_f32_16x16x32_bf16(a[mi][1][0], b10, acc[mi][ni], 0, 0, 0);
                acc[mi][ni] = __builtin_amdgcn_mfma_f32_16x16x32_bf16(a[mi][1][1], b11, acc[mi][ni], 0, 0, 0);
            }
        }
    }

    // store ReLU'd bf16 into padded channel-last hidden
    int pxq = (lane >> 4) << 2;
    __hip_bfloat16* hb = hidden + (size_t)(n * 64 + r) * 66 * 64;
    #pragma unroll
    for (int mi = 0; mi < 2; mi++) {
        #pragma unroll
        for (int ni = 0; ni < 4; ni++) {
            int co = ni * 16 + lr;
            #pragma unroll
            for (int j = 0; j < 4; j++) {
                int px = m0 + mi * 16 + pxq + j;
                float v = acc[mi][ni][j];
                v = v < 0.f ? 0.f : v;
                hb[(size_t)(px + 1) * 64 + co] = __float2bfloat16(v);
            }
        }
    }
}

// ---------- conv2 via MFMA: 64->6 3x3 pad1, M=64 x N=16(6) x K=576 per row ----------
// grid 512 = n(32)*rowquad(16); 4 waves = 4 rows
__global__ __launch_bounds__(256) void k_conv2_mfma(const __hip_bfloat16* __restrict__ hidden,
                                                    const __hip_bfloat16* __restrict__ W2b,
                                                    const __hip_bfloat16* __restrict__ zrow,
                                                    const float* __restrict__ b2,
                                                    float* __restrict__ off)
{
    int bid = blockIdx.x;
    int rq = bid & 15;
    int n = bid >> 4;
    int tid = threadIdx.x;
    int wv = tid >> 6;
    int lane = tid & 63;
    int r = rq * 4 + wv;
    int lr = lane & 15;
    int lk = (lane >> 4) << 3;

    const __hip_bfloat16* hbase = hidden + (size_t)n * 270336;

    float bb = (lr < 6) ? b2[lr] : 0.f;
    f32x4 acc[4];
    #pragma unroll
    for (int mi = 0; mi < 4; mi++) acc[mi] = (f32x4){bb, bb, bb, bb};

    #pragma unroll
    for (int tap = 0; tap < 9; tap++) {
        const int kh = tap / 3, kw = tap - (tap / 3) * 3;
        int rr = r + kh - 1;
        bool ok = (rr >= 0) && (rr < 64);
        const __hip_bfloat16* hr = ok ? (hbase + (size_t)rr * 4224) : zrow;
        const __hip_bfloat16* bw = W2b + ((size_t)tap * 16 + lr) * 64 + lk;
        short8v b0 = *(const short8v*)(bw);
        short8v b1v = *(const short8v*)(bw + 32);
        #pragma unroll
        for (int mi = 0; mi < 4; mi++) {
            int abase = (mi * 16 + lr + kw) * 64 + lk;
            short8v a0 = *(const short8v*)(hr + abase);
            short8v a1 = *(const short8v*)(hr + abase + 32);
            acc[mi] = __builtin_amdgcn_mfma_f32_16x16x32_bf16(a0, b0, acc[mi], 0, 0, 0);
            acc[mi] = __builtin_amdgcn_mfma_f32_16x16x32_bf16(a1, b1v, acc[mi], 0, 0, 0);
        }
    }
    if (lr < 6) {
        int pxq = (lane >> 4) << 2;
        #pragma unroll
        for (int mi = 0; mi < 4; mi++) {
            #pragma unroll
            for (int j = 0; j < 4; j++) {
                int px = mi * 16 + pxq + j;
                off[((size_t)n * 6 + lr) * 4096 + r * 64 + px] = acc[mi][j];
            }
        }
    }
}

// ---------- 1x1x1 down conv ----------
__global__ __launch_bounds__(256) void k_down(const float* __restrict__ x,
                                              const float* __restrict__ dw,
                                              float* __restrict__ xa)
{
    int gid = blockIdx.x * 256 + threadIdx.x;   // 131072
    int hw = gid & 4095;
    int bt = gid >> 12;
    int b = bt >> 4, t = bt & 15;
    float a0 = 0.f, a1 = 0.f, a2 = 0.f, a3 = 0.f;
    const float* xp = x + (((size_t)b * 64) * 16 + t) * 4096 + hw;
    for (int c = 0; c < 64; c++) {
        float v = xp[(size_t)c * 65536];
        a0 = fmaf(v, dw[c], a0);
        a1 = fmaf(v, dw[64 + c], a1);
        a2 = fmaf(v, dw[128 + c], a2);
        a3 = fmaf(v, dw[192 + c], a3);
    }
    size_t base = (((size_t)b * 4) * 16 + t) * 4096 + hw;
    xa[base] = a0;
    xa[base + 65536] = a1;
    xa[base + 131072] = a2;
    xa[base + 196608] = a3;
}

// ---------- grouped dilated 3D convs, 3 scales, weighted sum ----------
__global__ __launch_bounds__(256) void k_agg(const float* __restrict__ xa,
                                             const float* __restrict__ w1, const float* __restrict__ b1,
                                             const float* __restrict__ w2, const float* __restrict__ b2,
                                             const float* __restrict__ w3, const float* __restrict__ b3,
                                             const float* __restrict__ aw,
                                             float* __restrict__ agg)
{
    int gid = blockIdx.x * 256 + threadIdx.x;   // 524288
    int hw = gid & 4095;
    int rest = gid >> 12;
    int t = rest & 15;
    int g = (rest >> 4) & 3;
    int b = rest >> 6;
    int h = hw >> 6, w = hw & 63;
    const float* base = xa + ((size_t)(b * 4 + g) * 16) * 4096;
    const float* ws0 = w1 + g * 81;
    const float* ws1 = w2 + g * 81;
    const float* ws2 = w3 + g * 81;
    float acc0 = b1[g], acc1 = b2[g], acc2 = b3[g];
    for (int kd = 0; kd < 9; kd++) {
        int d = t + kd - 4;
        if (d < 0 || d > 15) continue;
        const float* fr = base + (size_t)d * 4096;
        #pragma unroll
        for (int kh = 0; kh < 3; kh++) {
            #pragma unroll
            for (int kw = 0; kw < 3; kw++) {
                int widx = kd * 9 + kh * 3 + kw;
                {
                    int yy = h + (kh - 1), xx = w + (kw - 1);
                    if (yy >= 0 && yy < 64 && xx >= 0 && xx < 64)
                        acc0 = fmaf(fr[yy * 64 + xx], ws0[widx], acc0);
                }
                {
                    int yy = h + (kh - 1) * 2, xx = w + (kw - 1) * 2;
                    if (yy >= 0 && yy < 64 && xx >= 0 && xx < 64)
                        acc1 = fmaf(fr[yy * 64 + xx], ws1[widx], acc1);
                }
                {
                    int yy = h + (kh - 1) * 3, xx = w + (kw - 1) * 3;
                    if (yy >= 0 && yy < 64 && xx >= 0 && xx < 64)
                        acc2 = fmaf(fr[yy * 64 + xx], ws2[widx], acc2);
                }
            }
        }
    }
    agg[gid] = acc0 * aw[0] + acc1 * aw[1] + acc2 * aw[2];
}

// ---------- deformable correlation -> stats (avg,max,var), bf16 vectorized gathers ----------
__global__ __launch_bounds__(256) void k_corr(const __hip_bfloat16* __restrict__ xT,
                                              const float* __restrict__ off,
                                              float* __restrict__ stats, int dir)
{
    int gid = blockIdx.x * 256 + threadIdx.x;   // 131072
    int hw = gid & 4095;
    int n = gid >> 12;
    int b = n >> 4, t = n & 15;
    int t2 = (dir > 0) ? min(t + 1, 15) : max(t - 1, 0);
    int n2 = b * 16 + t2;
    int h = hw >> 6, w = hw & 63;

    const __hip_bfloat16* xf = xT + (size_t)n * 270336 + h * 4224 + (w + 1) * 64;
    const __hip_bfloat16* yf = xT + (size_t)n2 * 270336;

    Samp sp[3];
    #pragma unroll
    for (int s = 0; s < 3; s++) {
        float ox = off[((size_t)n * 6 + 2 * s) * 4096 + hw];
        float oy = off[((size_t)n * 6 + 2 * s + 1) * 4096 + hw];
        sp[s] = make_samp(ox, oy, w, h);
    }

    float ac[3][4];
    #pragma unroll
    for (int s = 0; s < 3; s++)
        #pragma unroll
        for (int q = 0; q < 4; q++) ac[s][q] = 0.f;

    for (int cc = 0; cc < 64; cc += 8) {
        short8v xv = *(const short8v*)(xf + cc);
        #pragma unroll
        for (int s = 0; s < 3; s++) {
            short8v v0 = *(const short8v*)(yf + sp[s].o0 + cc);
            short8v v1 = *(const short8v*)(yf + sp[s].o1 + cc);
            short8v v2 = *(const short8v*)(yf + sp[s].o2 + cc);
            short8v v3 = *(const short8v*)(yf + sp[s].o3 + cc);
            #pragma unroll
            for (int e = 0; e < 8; e++) {
                float xe = bf2f(xv[e]);
                ac[s][0] = fmaf(xe, bf2f(v0[e]), ac[s][0]);
                ac[s][1] = fmaf(xe, bf2f(v1[e]), ac[s][1]);
                ac[s][2] = fmaf(xe, bf2f(v2[e]), ac[s][2]);
                ac[s][3] = fmaf(xe, bf2f(v3[e]), ac[s][3]);
            }
        }
    }
    float c[3];
    #pragma unroll
    for (int s = 0; s < 3; s++)
        c[s] = (ac[s][0] * sp[s].w0 + ac[s][1] * sp[s].w1 + ac[s][2] * sp[s].w2 + ac[s][3] * sp[s].w3) * (1.0f / 64.0f);
    float avg = (c[0] + c[1] + c[2]) * (1.0f / 3.0f);
    float mx = fmaxf(c[0], fmaxf(c[1], c[2]));
    float d0 = c[0] - avg, d1 = c[1] - avg, d2 = c[2] - avg;
    float var = (d0 * d0 + d1 * d1 + d2 * d2) * 0.5f;   // ddof=1
    stats[(size_t)n * 4096 + hw] = avg;
    stats[131072 + (size_t)n * 4096 + hw] = mx;
    stats[262144 + (size_t)n * 4096 + hw] = var;
}

// ---------- per-pixel feat multiplier A = sigmoid(avg*attn)-0.5 ----------
__device__ __forceinline__ float attn_val(const float* __restrict__ stats, int n, int hw,
                                          const float* __restrict__ cfw1,
                                          const float* __restrict__ cfw2)
{
    int h = hw >> 6, w = hw & 63;
    const float* avg = stats + (size_t)n * 4096;
    const float* mx  = stats + 131072 + (size_t)n * 4096;
    const float* var = stats + 262144 + (size_t)n * 4096;
    float s = 0.f;
    #pragma unroll
    for (int k = 0; k < 9; k++) {
        int kh = k / 3 - 1, kw = k - (k / 3) * 3 - 1;
        int yy = h + kh, xx = w + kw;
        if (yy >= 0 && yy < 64 && xx >= 0 && xx < 64) {
            int p = yy * 64 + xx;
            s += avg[p] * cfw1[k] + mx[p] * cfw1[9 + k] + var[p] * cfw2[k];
        }
    }
    float attn = sigmoidf_(s);
    return sigmoidf_(avg[hw] * attn) - 0.5f;
}

// ---------- final: bf16 vectorized warps + attn + long-term ----------
__global__ __launch_bounds__(256) void k_final(const __hip_bfloat16* __restrict__ xT,
                                               const float* __restrict__ off_l,
                                               const float* __restrict__ off_r,
                                               const float* __restrict__ stats_l,
                                               const float* __restrict__ stats_r,
                                               const float* __restrict__ cfw1,
                                               const float* __restrict__ cfw2,
                                               const float* __restrict__ agg,
                                               const float* __restrict__ backw,
                                               const float* __restrict__ fusw,
                                               float* __restrict__ out)
{
    int gid = blockIdx.x * 256 + threadIdx.x;   // 131072
    int hw = gid & 4095;
    int n = gid >> 12;
    int b = n >> 4, t = n & 15;
    int tl = min(t + 1, 15), tr = max(t - 1, 0);
    int nl = b * 16 + tl, nr = b * 16 + tr;
    int h = hw >> 6, w = hw & 63;

    float oxl = off_l[((size_t)n * 6 + 0) * 4096 + hw];
    float oyl = off_l[((size_t)n * 6 + 1) * 4096 + hw];
    float oxr = off_r[((size_t)n * 6 + 0) * 4096 + hw];
    float oyr = off_r[((size_t)n * 6 + 1) * 4096 + hw];
    Samp sl = make_samp(oxl, oyl, w, h);
    Samp sr = make_samp(oxr, oyr, w, h);

    const __hip_bfloat16* lf = xT + (size_t)nl * 270336;
    const __hip_bfloat16* rf = xT + (size_t)nr * 270336;

    float Al = attn_val(stats_l, n, hw, cfw1, cfw2) * fusw[0];
    float Ar = attn_val(stats_r, n, hw, cfw1, cfw2) * fusw[1];

    float ag0 = agg[((size_t)(b * 4 + 0) * 16 + t) * 4096 + hw];
    float ag1 = agg[((size_t)(b * 4 + 1) * 16 + t) * 4096 + hw];
    float ag2 = agg[((size_t)(b * 4 + 2) * 16 + t) * 4096 + hw];
    float ag3 = agg[((size_t)(b * 4 + 3) * 16 + t) * 4096 + hw];

    for (int cc = 0; cc < 64; cc += 8) {
        short8v l0 = *(const short8v*)(lf + sl.o0 + cc);
        short8v l1 = *(const short8v*)(lf + sl.o1 + cc);
        short8v l2 = *(const short8v*)(lf + sl.o2 + cc);
        short8v l3 = *(const short8v*)(lf + sl.o3 + cc);
        short8v r0 = *(const short8v*)(rf + sr.o0 + cc);
        short8v r1 = *(const short8v*)(rf + sr.o1 + cc);
        short8v r2 = *(const short8v*)(rf + sr.o2 + cc);
        short8v r3 = *(const short8v*)(rf + sr.o3 + cc);
        #pragma unroll
        for (int e = 0; e < 8; e++) {
            int c = cc + e;
            float wl = sl.w0 * bf2f(l0[e]) + sl.w1 * bf2f(l1[e]) + sl.w2 * bf2f(l2[e]) + sl.w3 * bf2f(l3[e]);
            float wr = sr.w0 * bf2f(r0[e]) + sr.w1 * bf2f(r1[e]) + sr.w2 * bf2f(r2[e]) + sr.w3 * bf2f(r3[e]);
            float lt = sigmoidf_(ag0 * backw[c * 4 + 0] + ag1 * backw[c * 4 + 1]
                               + ag2 * backw[c * 4 + 2] + ag3 * backw[c * 4 + 3]) - 0.5f;
            out[(((size_t)b * 64 + c) * 16 + t) * 4096 + hw] = (wl * Al + wr * Ar) * lt;
        }
    }
}

extern "C" void kernel_launch(void* const* d_in, const int* in_sizes, int n_in,
                              void* d_out, int out_size, void* d_ws, size_t ws_size,
                              hipStream_t stream)
{
    const float* x     = (const float*)d_in[0];
    const float* lw1   = (const float*)d_in[1];
    const float* lb1   = (const float*)d_in[2];
    const float* lw2   = (const float*)d_in[3];
    const float* lb2   = (const float*)d_in[4];
    const float* rw1   = (const float*)d_in[5];
    const float* rb1   = (const float*)d_in[6];
    const float* rw2   = (const float*)d_in[7];
    const float* rb2   = (const float*)d_in[8];
    const float* cfw1  = (const float*)d_in[9];
    const float* cfw2  = (const float*)d_in[10];
    const float* downw = (const float*)d_in[11];
    const float* sa1w  = (const float*)d_in[12];
    const float* sa1b  = (const float*)d_in[13];
    const float* sa2w  = (const float*)d_in[14];
    const float* sa2b  = (const float*)d_in[15];
    const float* sa3w  = (const float*)d_in[16];
    const float* sa3b  = (const float*)d_in[17];
    const float* aggw  = (const float*)d_in[18];
    const float* backw = (const float*)d_in[19];
    const float* fusw  = (const float*)d_in[20];
    float* out = (float*)d_out;

    // fp32 region
    float* ws      = (float*)d_ws;
    float* x_agg   = ws;                    // 524288 f
    float* agg     = x_agg + 524288;        // 524288 f
    float* off_l   = agg + 524288;          // 786432 f
    float* off_r   = off_l + 786432;        // 786432 f
    float* stats_l = off_r + 786432;        // 393216 f
    float* stats_r = stats_l + 393216;      // 393216 f
    // bf16 region
    __hip_bfloat16* hidden = (__hip_bfloat16*)(stats_r + 393216);  // 8650752 bf16 (padded)
    __hip_bfloat16* xT     = hidden + 8650752;                     // 8650752 bf16
    __hip_bfloat16* Wmisc  = xT + 8650752;                         // 170112 bf16
    __hip_bfloat16* Wb     = Wmisc;                 // conv1 weights, both sides
    __hip_bfloat16* zrow   = Wmisc + 147456;        // 4224 zeros
    __hip_bfloat16* W2bL   = Wmisc + 151680;        // 9216
    __hip_bfloat16* W2bR   = W2bL + 9216;           // 9216

    k_prep_x<<<2048, 256, 0, stream>>>(x, xT);
    k_prep_w<<<1689, 256, 0, stream>>>(lw1, rw1, lw2, rw2, Wmisc, hidden);

    k_down<<<512, 256, 0, stream>>>(x, downw, x_agg);
    k_agg<<<2048, 256, 0, stream>>>(x_agg, sa1w, sa1b, sa2w, sa2b, sa3w, sa3b, aggw, agg);

    // left branch
    k_conv1_mfma<<<1024, 256, 0, stream>>>(xT, Wb, zrow, lb1, hidden, +1);
    k_conv2_mfma<<<512, 256, 0, stream>>>(hidden, W2bL, zrow, lb2, off_l);
    k_corr<<<512, 256, 0, stream>>>(xT, off_l, stats_l, +1);

    // right branch (reuses hidden; pad cols stay zero)
    k_conv1_mfma<<<1024, 256, 0, stream>>>(xT, Wb + 73728, zrow, rb1, hidden, -1);
    k_conv2_mfma<<<512, 256, 0, stream>>>(hidden, W2bR, zrow, rb2, off_r);
    k_corr<<<512, 256, 0, stream>>>(xT, off_r, stats_r, -1);

    k_final<<<512, 256, 0, stream>>>(xT, off_l, off_r, stats_l, stats_r, cfw1, cfw2,
                                     agg, backw, fusw, out);
}

// Round 4
// 302.010 us; speedup vs baseline: 3.7496x; 1.4028x over previous
//
#include <hip/hip_runtime.h>
#include <hip/hip_bf16.h>
#include <math.h>

// Layout constants: B=2, C=64, T=16, H=W=64, S=3, r=4
// x: ((b*64+c)*16+t)*4096 + h*64+w ; frame n in [0,32): b=n>>4, t=n&15
// xT bf16: [n][h 0..63][w' 0..65][c 0..63], w'=w+1, cols 0/65 zero. frame stride 270336, row stride 4224
// hidden bf16: [n][r 0..63][px' 0..65][co 0..63], pad cols zero. frame stride 270336, row stride 4224
// conv1 weights (Wb): per side, per tap: 64co x 128ci bf16, SWIZZLED: el = co*128 + (ci ^ ((co&15)<<3))

typedef __attribute__((ext_vector_type(8))) short short8v;
typedef __attribute__((ext_vector_type(4))) float f32x4;

__device__ __forceinline__ float sigmoidf_(float v) {
    return 1.0f / (1.0f + expf(-v));
}

__device__ __forceinline__ float bf2f(short s) {
    union { unsigned u; float f; } z;
    z.u = ((unsigned)(unsigned short)s) << 16;
    return z.f;
}

// async global->LDS, 16B per lane; l must be wave-uniform base (HW adds lane*16)
__device__ __forceinline__ void gll16(const __hip_bfloat16* g, __hip_bfloat16* l) {
    __builtin_amdgcn_global_load_lds((const __attribute__((address_space(1))) unsigned int*)(const void*)g,
                                     (__attribute__((address_space(3))) unsigned int*)(void*)l,
                                     16, 0, 0);
}

// Bilinear sample setup matching reference grid_sample semantics; offsets in xT/channel-last coords.
struct Samp { int o0, o1, o2, o3; float w0, w1, w2, w3; };

__device__ __forceinline__ Samp make_samp(float ox, float oy, int w, int h) {
    float bx = (2.0f * (float)w) / 63.0f - 1.0f;
    float by = (2.0f * (float)h) / 63.0f - 1.0f;
    float vx = bx + ox / 63.0f;
    float vy = by + oy / 63.0f;
    float gx = ((vx + 1.0f) * 64.0f - 1.0f) * 0.5f;
    float gy = ((vy + 1.0f) * 64.0f - 1.0f) * 0.5f;
    float fx = floorf(gx), fy = floorf(gy);
    float wx = gx - fx, wy = gy - fy;
    int x0 = (int)fx, y0 = (int)fy;
    int x1 = x0 + 1, y1 = y0 + 1;
    bool vx0 = (x0 >= 0) && (x0 < 64), vx1 = (x1 >= 0) && (x1 < 64);
    bool vy0 = (y0 >= 0) && (y0 < 64), vy1 = (y1 >= 0) && (y1 < 64);
    int cx0 = min(max(x0, 0), 63), cx1 = min(max(x1, 0), 63);
    int cy0 = min(max(y0, 0), 63), cy1 = min(max(y1, 0), 63);
    Samp s;
    s.o0 = cy0 * 4224 + (cx0 + 1) * 64; s.w0 = (1.0f - wx) * (1.0f - wy) * ((vx0 && vy0) ? 1.0f : 0.0f);
    s.o1 = cy0 * 4224 + (cx1 + 1) * 64; s.w1 = wx * (1.0f - wy) * ((vx1 && vy0) ? 1.0f : 0.0f);
    s.o2 = cy1 * 4224 + (cx0 + 1) * 64; s.w2 = (1.0f - wx) * wy * ((vx0 && vy1) ? 1.0f : 0.0f);
    s.o3 = cy1 * 4224 + (cx1 + 1) * 64; s.w3 = wx * wy * ((vx1 && vy1) ? 1.0f : 0.0f);
    return s;
}

// ---------- prep: x fp32 -> xT bf16 channel-last padded ----------
__global__ __launch_bounds__(256) void k_prep_x(const float* __restrict__ x,
                                                __hip_bfloat16* __restrict__ xT)
{
    int bid = blockIdx.x;          // 2048 = n*64 + h
    int h = bid & 63;
    int n = bid >> 6;
    int b = n >> 4, t = n & 15;
    __shared__ float s[64][65];
    int tid = threadIdx.x;
    for (int idx = tid; idx < 4096; idx += 256) {
        int c = idx >> 6, w = idx & 63;
        s[c][w] = x[(((size_t)b * 64 + c) * 16 + t) * 4096 + h * 64 + w];
    }
    __syncthreads();
    __hip_bfloat16* op = xT + ((size_t)n * 64 + h) * 4224;
    for (int idx = tid; idx < 4224; idx += 256) {
        int wp = idx >> 6, c = idx & 63;
        float v = (wp == 0 || wp == 65) ? 0.f : s[c][wp - 1];
        op[idx] = __float2bfloat16(v);
    }
}

// ---------- prep: conv1 weights (swizzled), zero-row, conv2 weights, hidden pad cols ----------
// Wmisc layout: [Wb 147456][zrow 4224][W2b_L 9216][W2b_R 9216]
__global__ __launch_bounds__(256) void k_prep_w(const float* __restrict__ wl1,
                                                const float* __restrict__ wr1,
                                                const float* __restrict__ wl2,
                                                const float* __restrict__ wr2,
                                                __hip_bfloat16* __restrict__ Wmisc,
                                                __hip_bfloat16* __restrict__ hidden)
{
    int idx = blockIdx.x * 256 + threadIdx.x;    // 1689*256 = 432384, used 432256
    if (idx < 147456) {
        // conv1: [side][tap 9][co 64][ci 128], ci position XOR-swizzled for LDS bank spread
        int side = (idx >= 73728) ? 1 : 0;
        int i = idx - side * 73728;
        int ci = i & 127;
        int co = (i >> 7) & 63;
        int tap = i >> 13;
        const float* w = side ? wr1 : wl1;
        float v = w[((size_t)co * 128 + ci) * 9 + tap];
        int pos = side * 73728 + tap * 8192 + co * 128 + (ci ^ ((co & 15) << 3));
        Wmisc[pos] = __float2bfloat16(v);
    } else if (idx < 151680) {
        Wmisc[idx] = __float2bfloat16(0.f);      // zero row (4224)
    } else if (idx < 170112) {
        // conv2: [side][tap 9][co 16 pad][ci 64]
        int i2 = idx - 151680;
        int side = i2 / 9216;
        int j = i2 - side * 9216;
        int tap = j >> 10;
        int rem = j & 1023;
        int co = rem >> 6;
        int ci = rem & 63;
        const float* w = side ? wr2 : wl2;
        float v = (co < 6) ? w[((size_t)co * 64 + ci) * 9 + tap] : 0.f;
        Wmisc[idx] = __float2bfloat16(v);
    } else if (idx < 432256) {
        // hidden pad columns px' in {0,65}
        int i3 = idx - 170112;                   // 262144 = 32*64*2*64
        int co = i3 & 63;
        int sel = (i3 >> 6) & 1;
        int rr = (i3 >> 7) & 63;
        int nn = i3 >> 13;
        hidden[((size_t)(nn * 64 + rr) * 66 + (sel ? 65 : 0)) * 64 + co] = __float2bfloat16(0.f);
    }
}

// ---------- conv1 via MFMA: 128->64 3x3 pad1 + ReLU; per-tap B tile in LDS, 2-phase dbuf ----------
// grid 1024 = n(32)*rowpair(32); 4 waves = row(2) x m0(2); wave tile M=32 x N=64
__global__ __launch_bounds__(256) void k_conv1_mfma(const __hip_bfloat16* __restrict__ xT,
                                                    const __hip_bfloat16* __restrict__ Wb,
                                                    const __hip_bfloat16* __restrict__ zrow,
                                                    const float* __restrict__ b1,
                                                    __hip_bfloat16* __restrict__ hidden,
                                                    int dir)
{
    __shared__ __hip_bfloat16 sB[2][8192];       // 2 x 16KB tap weight tiles

    int bid = blockIdx.x;
    int rp = bid & 31;
    int n = bid >> 5;
    int b = n >> 4, t = n & 15;
    int t2 = (dir > 0) ? min(t + 1, 15) : max(t - 1, 0);
    int n2 = b * 16 + t2;

    int tid = threadIdx.x;
    int wv = tid >> 6;
    int lane = tid & 63;
    int r = rp * 2 + (wv & 1);
    int m0 = (wv >> 1) * 32;
    int lr = lane & 15;
    int q = lane >> 4;           // 0..3
    int lk = q << 3;             // element k offset within 64-ci frame block

    const __hip_bfloat16* fA0 = xT + (size_t)n * 270336;
    const __hip_bfloat16* fA1 = xT + (size_t)n2 * 270336;

    f32x4 acc[2][4];
    #pragma unroll
    for (int ni = 0; ni < 4; ni++) {
        float bb = b1[ni * 16 + lr];
        acc[0][ni] = (f32x4){bb, bb, bb, bb};
        acc[1][ni] = (f32x4){bb, bb, bb, bb};
    }

    // swizzled byte offsets within a row for B ds_reads: (khalf*128 + ks*64 + q*16) ^ (lr<<4)
    int kx[2][2];
    #pragma unroll
    for (int khalf = 0; khalf < 2; khalf++)
        #pragma unroll
        for (int ks = 0; ks < 2; ks++)
            kx[khalf][ks] = ((khalf << 7) + (ks << 6) + (q << 4)) ^ (lr << 4);

    // prologue: stage tap 0 into buf 0
    #pragma unroll
    for (int i = 0; i < 4; i++)
        gll16(Wb + (size_t)(i * 2048 + wv * 512 + lane * 8), &sB[0][i * 2048 + wv * 512]);
    __syncthreads();

    #pragma unroll
    for (int tap = 0; tap < 9; tap++) {
        const int cur = tap & 1;
        if (tap < 8) {
            const __hip_bfloat16* wsrc = Wb + ((size_t)(tap + 1) << 13);
            #pragma unroll
            for (int i = 0; i < 4; i++)
                gll16(wsrc + (size_t)(i * 2048 + wv * 512 + lane * 8), &sB[cur ^ 1][i * 2048 + wv * 512]);
        }
        const int kh = tap / 3, kw = tap - (tap / 3) * 3;
        int rr = r + kh - 1;
        bool ok = (rr >= 0) && (rr < 64);
        const __hip_bfloat16* r0 = ok ? (fA0 + rr * 4224) : zrow;
        const __hip_bfloat16* r1 = ok ? (fA1 + rr * 4224) : zrow;
        int abase = (m0 + lr + kw) * 64 + lk;
        const char* sbc = (const char*)&sB[cur][0];

        #pragma unroll
        for (int khalf = 0; khalf < 2; khalf++) {
            const __hip_bfloat16* ar = khalf ? r1 : r0;
            short8v a00 = *(const short8v*)(ar + abase);            // mi0 ks0
            short8v a01 = *(const short8v*)(ar + abase + 32);       // mi0 ks1
            short8v a10 = *(const short8v*)(ar + abase + 1024);     // mi1 ks0
            short8v a11 = *(const short8v*)(ar + abase + 1056);     // mi1 ks1
            #pragma unroll
            for (int ni = 0; ni < 4; ni++) {
                int rowb = ni * 4096 + lr * 256;
                short8v b0 = *(const short8v*)(sbc + (rowb + kx[khalf][0]));
                short8v b1v = *(const short8v*)(sbc + (rowb + kx[khalf][1]));
                acc[0][ni] = __builtin_amdgcn_mfma_f32_16x16x32_bf16(a00, b0, acc[0][ni], 0, 0, 0);
                acc[1][ni] = __builtin_amdgcn_mfma_f32_16x16x32_bf16(a10, b0, acc[1][ni], 0, 0, 0);
                acc[0][ni] = __builtin_amdgcn_mfma_f32_16x16x32_bf16(a01, b1v, acc[0][ni], 0, 0, 0);
                acc[1][ni] = __builtin_amdgcn_mfma_f32_16x16x32_bf16(a11, b1v, acc[1][ni], 0, 0, 0);
            }
        }
        __syncthreads();
    }

    // store ReLU'd bf16 into padded channel-last hidden
    int pxq = q << 2;
    __hip_bfloat16* hb = hidden + (size_t)(n * 64 + r) * 66 * 64;
    #pragma unroll
    for (int mi = 0; mi < 2; mi++) {
        #pragma unroll
        for (int ni = 0; ni < 4; ni++) {
            int co = ni * 16 + lr;
            #pragma unroll
            for (int j = 0; j < 4; j++) {
                int px = m0 + mi * 16 + pxq + j;
                float v = acc[mi][ni][j];
                v = v < 0.f ? 0.f : v;
                hb[(size_t)(px + 1) * 64 + co] = __float2bfloat16(v);
            }
        }
    }
}

// ---------- conv2 via MFMA: 64->6 3x3 pad1, M=64 x N=16(6) x K=576 per row ----------
__global__ __launch_bounds__(256) void k_conv2_mfma(const __hip_bfloat16* __restrict__ hidden,
                                                    const __hip_bfloat16* __restrict__ W2b,
                                                    const __hip_bfloat16* __restrict__ zrow,
                                                    const float* __restrict__ b2,
                                                    float* __restrict__ off)
{
    int bid = blockIdx.x;
    int rq = bid & 15;
    int n = bid >> 4;
    int tid = threadIdx.x;
    int wv = tid >> 6;
    int lane = tid & 63;
    int r = rq * 4 + wv;
    int lr = lane & 15;
    int lk = (lane >> 4) << 3;

    const __hip_bfloat16* hbase = hidden + (size_t)n * 270336;

    float bb = (lr < 6) ? b2[lr] : 0.f;
    f32x4 acc[4];
    #pragma unroll
    for (int mi = 0; mi < 4; mi++) acc[mi] = (f32x4){bb, bb, bb, bb};

    #pragma unroll
    for (int tap = 0; tap < 9; tap++) {
        const int kh = tap / 3, kw = tap - (tap / 3) * 3;
        int rr = r + kh - 1;
        bool ok = (rr >= 0) && (rr < 64);
        const __hip_bfloat16* hr = ok ? (hbase + (size_t)rr * 4224) : zrow;
        const __hip_bfloat16* bw = W2b + ((size_t)tap * 16 + lr) * 64 + lk;
        short8v b0 = *(const short8v*)(bw);
        short8v b1v = *(const short8v*)(bw + 32);
        #pragma unroll
        for (int mi = 0; mi < 4; mi++) {
            int abase = (mi * 16 + lr + kw) * 64 + lk;
            short8v a0 = *(const short8v*)(hr + abase);
            short8v a1 = *(const short8v*)(hr + abase + 32);
            acc[mi] = __builtin_amdgcn_mfma_f32_16x16x32_bf16(a0, b0, acc[mi], 0, 0, 0);
            acc[mi] = __builtin_amdgcn_mfma_f32_16x16x32_bf16(a1, b1v, acc[mi], 0, 0, 0);
        }
    }
    if (lr < 6) {
        int pxq = (lane >> 4) << 2;
        #pragma unroll
        for (int mi = 0; mi < 4; mi++) {
            #pragma unroll
            for (int j = 0; j < 4; j++) {
                int px = mi * 16 + pxq + j;
                off[((size_t)n * 6 + lr) * 4096 + r * 64 + px] = acc[mi][j];
            }
        }
    }
}

// ---------- 1x1x1 down conv ----------
__global__ __launch_bounds__(256) void k_down(const float* __restrict__ x,
                                              const float* __restrict__ dw,
                                              float* __restrict__ xa)
{
    int gid = blockIdx.x * 256 + threadIdx.x;   // 131072
    int hw = gid & 4095;
    int bt = gid >> 12;
    int b = bt >> 4, t = bt & 15;
    float a0 = 0.f, a1 = 0.f, a2 = 0.f, a3 = 0.f;
    const float* xp = x + (((size_t)b * 64) * 16 + t) * 4096 + hw;
    for (int c = 0; c < 64; c++) {
        float v = xp[(size_t)c * 65536];
        a0 = fmaf(v, dw[c], a0);
        a1 = fmaf(v, dw[64 + c], a1);
        a2 = fmaf(v, dw[128 + c], a2);
        a3 = fmaf(v, dw[192 + c], a3);
    }
    size_t base = (((size_t)b * 4) * 16 + t) * 4096 + hw;
    xa[base] = a0;
    xa[base + 65536] = a1;
    xa[base + 131072] = a2;
    xa[base + 196608] = a3;
}

// ---------- grouped dilated 3D convs, 3 scales, weighted sum ----------
__global__ __launch_bounds__(256) void k_agg(const float* __restrict__ xa,
                                             const float* __restrict__ w1, const float* __restrict__ b1,
                                             const float* __restrict__ w2, const float* __restrict__ b2,
                                             const float* __restrict__ w3, const float* __restrict__ b3,
                                             const float* __restrict__ aw,
                                             float* __restrict__ agg)
{
    int gid = blockIdx.x * 256 + threadIdx.x;   // 524288
    int hw = gid & 4095;
    int rest = gid >> 12;
    int t = rest & 15;
    int g = (rest >> 4) & 3;
    int b = rest >> 6;
    int h = hw >> 6, w = hw & 63;
    const float* base = xa + ((size_t)(b * 4 + g) * 16) * 4096;
    const float* ws0 = w1 + g * 81;
    const float* ws1 = w2 + g * 81;
    const float* ws2 = w3 + g * 81;
    float acc0 = b1[g], acc1 = b2[g], acc2 = b3[g];
    for (int kd = 0; kd < 9; kd++) {
        int d = t + kd - 4;
        if (d < 0 || d > 15) continue;
        const float* fr = base + (size_t)d * 4096;
        #pragma unroll
        for (int kh = 0; kh < 3; kh++) {
            #pragma unroll
            for (int kw = 0; kw < 3; kw++) {
                int widx = kd * 9 + kh * 3 + kw;
                {
                    int yy = h + (kh - 1), xx = w + (kw - 1);
                    if (yy >= 0 && yy < 64 && xx >= 0 && xx < 64)
                        acc0 = fmaf(fr[yy * 64 + xx], ws0[widx], acc0);
                }
                {
                    int yy = h + (kh - 1) * 2, xx = w + (kw - 1) * 2;
                    if (yy >= 0 && yy < 64 && xx >= 0 && xx < 64)
                        acc1 = fmaf(fr[yy * 64 + xx], ws1[widx], acc1);
                }
                {
                    int yy = h + (kh - 1) * 3, xx = w + (kw - 1) * 3;
                    if (yy >= 0 && yy < 64 && xx >= 0 && xx < 64)
                        acc2 = fmaf(fr[yy * 64 + xx], ws2[widx], acc2);
                }
            }
        }
    }
    agg[gid] = acc0 * aw[0] + acc1 * aw[1] + acc2 * aw[2];
}

// ---------- deformable correlation -> stats (avg,max,var), bf16 vectorized gathers ----------
__global__ __launch_bounds__(256) void k_corr(const __hip_bfloat16* __restrict__ xT,
                                              const float* __restrict__ off,
                                              float* __restrict__ stats, int dir)
{
    int gid = blockIdx.x * 256 + threadIdx.x;   // 131072
    int hw = gid & 4095;
    int n = gid >> 12;
    int b = n >> 4, t = n & 15;
    int t2 = (dir > 0) ? min(t + 1, 15) : max(t - 1, 0);
    int n2 = b * 16 + t2;
    int h = hw >> 6, w = hw & 63;

    const __hip_bfloat16* xf = xT + (size_t)n * 270336 + h * 4224 + (w + 1) * 64;
    const __hip_bfloat16* yf = xT + (size_t)n2 * 270336;

    Samp sp[3];
    #pragma unroll
    for (int s = 0; s < 3; s++) {
        float ox = off[((size_t)n * 6 + 2 * s) * 4096 + hw];
        float oy = off[((size_t)n * 6 + 2 * s + 1) * 4096 + hw];
        sp[s] = make_samp(ox, oy, w, h);
    }

    float ac[3][4];
    #pragma unroll
    for (int s = 0; s < 3; s++)
        #pragma unroll
        for (int qq = 0; qq < 4; qq++) ac[s][qq] = 0.f;

    for (int cc = 0; cc < 64; cc += 8) {
        short8v xv = *(const short8v*)(xf + cc);
        #pragma unroll
        for (int s = 0; s < 3; s++) {
            short8v v0 = *(const short8v*)(yf + sp[s].o0 + cc);
            short8v v1 = *(const short8v*)(yf + sp[s].o1 + cc);
            short8v v2 = *(const short8v*)(yf + sp[s].o2 + cc);
            short8v v3 = *(const short8v*)(yf + sp[s].o3 + cc);
            #pragma unroll
            for (int e = 0; e < 8; e++) {
                float xe = bf2f(xv[e]);
                ac[s][0] = fmaf(xe, bf2f(v0[e]), ac[s][0]);
                ac[s][1] = fmaf(xe, bf2f(v1[e]), ac[s][1]);
                ac[s][2] = fmaf(xe, bf2f(v2[e]), ac[s][2]);
                ac[s][3] = fmaf(xe, bf2f(v3[e]), ac[s][3]);
            }
        }
    }
    float c[3];
    #pragma unroll
    for (int s = 0; s < 3; s++)
        c[s] = (ac[s][0] * sp[s].w0 + ac[s][1] * sp[s].w1 + ac[s][2] * sp[s].w2 + ac[s][3] * sp[s].w3) * (1.0f / 64.0f);
    float avg = (c[0] + c[1] + c[2]) * (1.0f / 3.0f);
    float mx = fmaxf(c[0], fmaxf(c[1], c[2]));
    float d0 = c[0] - avg, d1 = c[1] - avg, d2 = c[2] - avg;
    float var = (d0 * d0 + d1 * d1 + d2 * d2) * 0.5f;   // ddof=1
    stats[(size_t)n * 4096 + hw] = avg;
    stats[131072 + (size_t)n * 4096 + hw] = mx;
    stats[262144 + (size_t)n * 4096 + hw] = var;
}

// ---------- per-pixel feat multiplier A = sigmoid(avg*attn)-0.5 ----------
__device__ __forceinline__ float attn_val(const float* __restrict__ stats, int n, int hw,
                                          const float* __restrict__ cfw1,
                                          const float* __restrict__ cfw2)
{
    int h = hw >> 6, w = hw & 63;
    const float* avg = stats + (size_t)n * 4096;
    const float* mx  = stats + 131072 + (size_t)n * 4096;
    const float* var = stats + 262144 + (size_t)n * 4096;
    float s = 0.f;
    #pragma unroll
    for (int k = 0; k < 9; k++) {
        int kh = k / 3 - 1, kw = k - (k / 3) * 3 - 1;
        int yy = h + kh, xx = w + kw;
        if (yy >= 0 && yy < 64 && xx >= 0 && xx < 64) {
            int p = yy * 64 + xx;
            s += avg[p] * cfw1[k] + mx[p] * cfw1[9 + k] + var[p] * cfw2[k];
        }
    }
    float attn = sigmoidf_(s);
    return sigmoidf_(avg[hw] * attn) - 0.5f;
}

// ---------- final: bf16 vectorized warps + attn + long-term ----------
__global__ __launch_bounds__(256) void k_final(const __hip_bfloat16* __restrict__ xT,
                                               const float* __restrict__ off_l,
                                               const float* __restrict__ off_r,
                                               const float* __restrict__ stats_l,
                                               const float* __restrict__ stats_r,
                                               const float* __restrict__ cfw1,
                                               const float* __restrict__ cfw2,
                                               const float* __restrict__ agg,
                                               const float* __restrict__ backw,
                                               const float* __restrict__ fusw,
                                               float* __restrict__ out)
{
    int gid = blockIdx.x * 256 + threadIdx.x;   // 131072
    int hw = gid & 4095;
    int n = gid >> 12;
    int b = n >> 4, t = n & 15;
    int tl = min(t + 1, 15), tr = max(t - 1, 0);
    int nl = b * 16 + tl, nr = b * 16 + tr;
    int h = hw >> 6, w = hw & 63;

    float oxl = off_l[((size_t)n * 6 + 0) * 4096 + hw];
    float oyl = off_l[((size_t)n * 6 + 1) * 4096 + hw];
    float oxr = off_r[((size_t)n * 6 + 0) * 4096 + hw];
    float oyr = off_r[((size_t)n * 6 + 1) * 4096 + hw];
    Samp sl = make_samp(oxl, oyl, w, h);
    Samp sr = make_samp(oxr, oyr, w, h);

    const __hip_bfloat16* lf = xT + (size_t)nl * 270336;
    const __hip_bfloat16* rf = xT + (size_t)nr * 270336;

    float Al = attn_val(stats_l, n, hw, cfw1, cfw2) * fusw[0];
    float Ar = attn_val(stats_r, n, hw, cfw1, cfw2) * fusw[1];

    float ag0 = agg[((size_t)(b * 4 + 0) * 16 + t) * 4096 + hw];
    float ag1 = agg[((size_t)(b * 4 + 1) * 16 + t) * 4096 + hw];
    float ag2 = agg[((size_t)(b * 4 + 2) * 16 + t) * 4096 + hw];
    float ag3 = agg[((size_t)(b * 4 + 3) * 16 + t) * 4096 + hw];

    for (int cc = 0; cc < 64; cc += 8) {
        short8v l0 = *(const short8v*)(lf + sl.o0 + cc);
        short8v l1 = *(const short8v*)(lf + sl.o1 + cc);
        short8v l2 = *(const short8v*)(lf + sl.o2 + cc);
        short8v l3 = *(const short8v*)(lf + sl.o3 + cc);
        short8v r0 = *(const short8v*)(rf + sr.o0 + cc);
        short8v r1 = *(const short8v*)(rf + sr.o1 + cc);
        short8v r2 = *(const short8v*)(rf + sr.o2 + cc);
        short8v r3 = *(const short8v*)(rf + sr.o3 + cc);
        #pragma unroll
        for (int e = 0; e < 8; e++) {
            int c = cc + e;
            float wl = sl.w0 * bf2f(l0[e]) + sl.w1 * bf2f(l1[e]) + sl.w2 * bf2f(l2[e]) + sl.w3 * bf2f(l3[e]);
            float wr = sr.w0 * bf2f(r0[e]) + sr.w1 * bf2f(r1[e]) + sr.w2 * bf2f(r2[e]) + sr.w3 * bf2f(r3[e]);
            float lt = sigmoidf_(ag0 * backw[c * 4 + 0] + ag1 * backw[c * 4 + 1]
                               + ag2 * backw[c * 4 + 2] + ag3 * backw[c * 4 + 3]) - 0.5f;
            out[(((size_t)b * 64 + c) * 16 + t) * 4096 + hw] = (wl * Al + wr * Ar) * lt;
        }
    }
}

extern "C" void kernel_launch(void* const* d_in, const int* in_sizes, int n_in,
                              void* d_out, int out_size, void* d_ws, size_t ws_size,
                              hipStream_t stream)
{
    const float* x     = (const float*)d_in[0];
    const float* lw1   = (const float*)d_in[1];
    const float* lb1   = (const float*)d_in[2];
    const float* lw2   = (const float*)d_in[3];
    const float* lb2   = (const float*)d_in[4];
    const float* rw1   = (const float*)d_in[5];
    const float* rb1   = (const float*)d_in[6];
    const float* rw2   = (const float*)d_in[7];
    const float* rb2   = (const float*)d_in[8];
    const float* cfw1  = (const float*)d_in[9];
    const float* cfw2  = (const float*)d_in[10];
    const float* downw = (const float*)d_in[11];
    const float* sa1w  = (const float*)d_in[12];
    const float* sa1b  = (const float*)d_in[13];
    const float* sa2w  = (const float*)d_in[14];
    const float* sa2b  = (const float*)d_in[15];
    const float* sa3w  = (const float*)d_in[16];
    const float* sa3b  = (const float*)d_in[17];
    const float* aggw  = (const float*)d_in[18];
    const float* backw = (const float*)d_in[19];
    const float* fusw  = (const float*)d_in[20];
    float* out = (float*)d_out;

    // fp32 region
    float* ws      = (float*)d_ws;
    float* x_agg   = ws;                    // 524288 f
    float* agg     = x_agg + 524288;        // 524288 f
    float* off_l   = agg + 524288;          // 786432 f
    float* off_r   = off_l + 786432;        // 786432 f
    float* stats_l = off_r + 786432;        // 393216 f
    float* stats_r = stats_l + 393216;      // 393216 f
    // bf16 region
    __hip_bfloat16* hidden = (__hip_bfloat16*)(stats_r + 393216);  // 8650752 bf16 (padded)
    __hip_bfloat16* xT     = hidden + 8650752;                     // 8650752 bf16
    __hip_bfloat16* Wmisc  = xT + 8650752;                         // 170112 bf16
    __hip_bfloat16* Wb     = Wmisc;                 // conv1 weights (swizzled), both sides
    __hip_bfloat16* zrow   = Wmisc + 147456;        // 4224 zeros
    __hip_bfloat16* W2bL   = Wmisc + 151680;        // 9216
    __hip_bfloat16* W2bR   = W2bL + 9216;           // 9216

    k_prep_x<<<2048, 256, 0, stream>>>(x, xT);
    k_prep_w<<<1689, 256, 0, stream>>>(lw1, rw1, lw2, rw2, Wmisc, hidden);

    k_down<<<512, 256, 0, stream>>>(x, downw, x_agg);
    k_agg<<<2048, 256, 0, stream>>>(x_agg, sa1w, sa1b, sa2w, sa2b, sa3w, sa3b, aggw, agg);

    // left branch
    k_conv1_mfma<<<1024, 256, 0, stream>>>(xT, Wb, zrow, lb1, hidden, +1);
    k_conv2_mfma<<<512, 256, 0, stream>>>(hidden, W2bL, zrow, lb2, off_l);
    k_corr<<<512, 256, 0, stream>>>(xT, off_l, stats_l, +1);

    // right branch (reuses hidden; pad cols stay zero)
    k_conv1_mfma<<<1024, 256, 0, stream>>>(xT, Wb + 73728, zrow, rb1, hidden, -1);
    k_conv2_mfma<<<512, 256, 0, stream>>>(hidden, W2bR, zrow, rb2, off_r);
    k_corr<<<512, 256, 0, stream>>>(xT, off_r, stats_r, -1);

    k_final<<<512, 256, 0, stream>>>(xT, off_l, off_r, stats_l, stats_r, cfw1, cfw2,
                                     agg, backw, fusw, out);
}